// Round 1
// baseline (1579.764 us; speedup 1.0000x reference)
//
#include <hip/hip_runtime.h>
#include <math.h>

namespace {

constexpr int nB = 8, nT = 512, nD = 1024, nH = 8, nDK = 128, nDV = 128, nC = 512, nM = 512;
constexpr int NROW = nB * nT;                  // 4096
constexpr float RTAU = 0.08838834764831845f;   // 1/sqrt(128)

__device__ __forceinline__ float blockReduce256(float v, float* sm) {
  int lane = threadIdx.x & 63, w = threadIdx.x >> 6;
#pragma unroll
  for (int off = 32; off; off >>= 1) v += __shfl_down(v, off);
  if (lane == 0) sm[w] = v;
  __syncthreads();
  float r = sm[0] + sm[1] + sm[2] + sm[3];
  __syncthreads();
  return r;
}

// ---------------- LayerNorm over D=1024, one block per (b,t) row ----------------
__global__ __launch_bounds__(256) void ln_kernel(const float* __restrict__ x,
                                                 const float* __restrict__ gw,
                                                 const float* __restrict__ bw,
                                                 float* __restrict__ xt) {
  __shared__ float sm[4];
  size_t row = blockIdx.x;
  float4 v = ((const float4*)(x + row * nD))[threadIdx.x];
  float mu = blockReduce256(v.x + v.y + v.z + v.w, sm) * (1.f / nD);
  float4 d = make_float4(v.x - mu, v.y - mu, v.z - mu, v.w - mu);
  float var = blockReduce256(d.x * d.x + d.y * d.y + d.z * d.z + d.w * d.w, sm) * (1.f / nD);
  float rs = rsqrtf(var + 1e-6f);
  float4 gg = ((const float4*)gw)[threadIdx.x];
  float4 bb = ((const float4*)bw)[threadIdx.x];
  float4 o = make_float4(d.x * rs * gg.x + bb.x, d.y * rs * gg.y + bb.y,
                         d.z * rs * gg.z + bb.z, d.w * rs * gg.w + bb.w);
  ((float4*)(xt + row * nD))[threadIdx.x] = o;
}

// ---------------- fp32 tiled GEMM: C[n][m] = sum_k A[n][k] * W[k][m] ----------------
// A: NROW x 1024 (row-major), W: 1024 x 1024 (row-major), C: NROW x 1024
// Tile 128x64, BK=16, 256 threads, 8x4 acc/thread. ACT: 0 none, 1 silu
template <int ACT>
__global__ __launch_bounds__(256) void gemm_kernel(const float* __restrict__ A,
                                                   const float* __restrict__ W,
                                                   float* __restrict__ Cp) {
  __shared__ float As[16][132];
  __shared__ float Bs[16][68];
  const int tid = threadIdx.x;
  const int m0 = blockIdx.x * 64;
  const int n0 = blockIdx.y * 128;
  const int tx = tid & 15, ty = tid >> 4;
  const int ai = tid >> 1, ak = (tid & 1) * 8;
  const int bk = tid >> 4, bj = (tid & 15) * 4;
  float acc[8][4];
#pragma unroll
  for (int i = 0; i < 8; ++i)
#pragma unroll
    for (int j = 0; j < 4; ++j) acc[i][j] = 0.f;

  for (int k0 = 0; k0 < nD; k0 += 16) {
    float4 a0 = *(const float4*)(A + (size_t)(n0 + ai) * nD + k0 + ak);
    float4 a1 = *(const float4*)(A + (size_t)(n0 + ai) * nD + k0 + ak + 4);
    float4 b4 = *(const float4*)(W + (size_t)(k0 + bk) * nD + m0 + bj);
    As[ak + 0][ai] = a0.x; As[ak + 1][ai] = a0.y; As[ak + 2][ai] = a0.z; As[ak + 3][ai] = a0.w;
    As[ak + 4][ai] = a1.x; As[ak + 5][ai] = a1.y; As[ak + 6][ai] = a1.z; As[ak + 7][ai] = a1.w;
    *(float4*)&Bs[bk][bj] = b4;
    __syncthreads();
#pragma unroll
    for (int kk = 0; kk < 16; ++kk) {
      float4 av0 = *(const float4*)&As[kk][ty * 8];
      float4 av1 = *(const float4*)&As[kk][ty * 8 + 4];
      float4 bv = *(const float4*)&Bs[kk][tx * 4];
      float a8[8] = {av0.x, av0.y, av0.z, av0.w, av1.x, av1.y, av1.z, av1.w};
      float b4a[4] = {bv.x, bv.y, bv.z, bv.w};
#pragma unroll
      for (int i = 0; i < 8; ++i)
#pragma unroll
        for (int j = 0; j < 4; ++j) acc[i][j] += a8[i] * b4a[j];
    }
    __syncthreads();
  }
#pragma unroll
  for (int i = 0; i < 8; ++i) {
    float4 o = make_float4(acc[i][0], acc[i][1], acc[i][2], acc[i][3]);
    if (ACT == 1) {
      o.x = o.x / (1.f + __expf(-o.x));
      o.y = o.y / (1.f + __expf(-o.y));
      o.z = o.z / (1.f + __expf(-o.z));
      o.w = o.w / (1.f + __expf(-o.w));
    }
    *(float4*)(Cp + (size_t)(n0 + ty * 8 + i) * nD + m0 + tx * 4) = o;
  }
}

// ---------------- headwise LN over 128, one wave per (b,t,h) row ----------------
template <int ADDXU>
__global__ __launch_bounds__(256) void hln_kernel(float* __restrict__ buf,
                                                  const float* __restrict__ xu) {
  int lane = threadIdx.x & 63;
  size_t row = (size_t)blockIdx.x * 4 + (threadIdx.x >> 6);
  float* p = buf + row * 128;
  float2 v = *(float2*)(p + lane * 2);
  float s = v.x + v.y;
#pragma unroll
  for (int off = 32; off; off >>= 1) s += __shfl_down(s, off);
  float mu = __shfl(s, 0) * (1.f / 128.f);
  float dx = v.x - mu, dy = v.y - mu;
  float q = dx * dx + dy * dy;
#pragma unroll
  for (int off = 32; off; off >>= 1) q += __shfl_down(q, off);
  float rs = rsqrtf(__shfl(q, 0) * (1.f / 128.f) + 1e-6f);
  float ox = dx * rs, oy = dy * rs;
  if (ADDXU) {
    int h = (int)(row & 7);
    ox += xu[h * 128 + lane * 2];
    oy += xu[h * 128 + lane * 2 + 1];
  }
  *(float2*)(p + lane * 2) = make_float2(ox, oy);
}

// ---------------- codebook transpose + norms ----------------
__global__ __launch_bounds__(128) void cbprep_kernel(const float* __restrict__ cb,
                                                     float* __restrict__ cbT,
                                                     float* __restrict__ cbn) {
  __shared__ float sm[2];
  const int hc = blockIdx.x;        // h*C + c
  const int h = hc >> 9, c = hc & 511;
  float v = cb[(size_t)hc * 128 + threadIdx.x];
  cbT[((size_t)h * 128 + threadIdx.x) * nC + c] = v;
  float s = v * v;
#pragma unroll
  for (int off = 32; off; off >>= 1) s += __shfl_down(s, off);
  if ((threadIdx.x & 63) == 0) sm[threadIdx.x >> 6] = s;
  __syncthreads();
  if (threadIdx.x == 0) cbn[hc] = sm[0] + sm[1];
}

// ---------------- VQ: argmin over 512 codes, write k_hat, per-block loss partial ----------------
__global__ __launch_bounds__(256) void vq_kernel(const float* __restrict__ kbuf,
                                                 const float* __restrict__ cb,
                                                 const float* __restrict__ cbT,
                                                 const float* __restrict__ cbn,
                                                 const float* __restrict__ mask,
                                                 float* __restrict__ khat,
                                                 float* __restrict__ blocksq) {
  __shared__ float ksh[8][128];
  __shared__ float knorm[8];
  __shared__ float rv[256];
  __shared__ int ri[256];
  __shared__ int zsel[8];
  __shared__ float lsel[8];
  const int tid = threadIdx.x;
  const int b = blockIdx.y >> 3, h = blockIdx.y & 7;
  const int t0 = blockIdx.x * 8;
  const int r = tid >> 5, d4 = (tid & 31) * 4;
  {
    const float* kr = kbuf + ((size_t)((b * nT + t0 + r) * nH + h)) * 128 + d4;
    float4 kv = *(const float4*)kr;
    *(float4*)&ksh[r][d4] = kv;
    float sq = kv.x * kv.x + kv.y * kv.y + kv.z * kv.z + kv.w * kv.w;
#pragma unroll
    for (int off = 16; off; off >>= 1) sq += __shfl_down(sq, off, 32);
    if ((tid & 31) == 0) knorm[r] = sq;
  }
  __syncthreads();
  const int c0 = tid, c1 = tid + 256;
  float acc0[8], acc1[8];
#pragma unroll
  for (int i = 0; i < 8; ++i) { acc0[i] = 0.f; acc1[i] = 0.f; }
  const float* cbTh = cbT + (size_t)h * 128 * nC;
#pragma unroll 2
  for (int d = 0; d < 128; ++d) {
    float w0 = cbTh[(size_t)d * nC + c0];
    float w1 = cbTh[(size_t)d * nC + c1];
#pragma unroll
    for (int rr = 0; rr < 8; ++rr) {
      float kv = ksh[rr][d];
      acc0[rr] += kv * w0;
      acc1[rr] += kv * w1;
    }
  }
  const float n0v = cbn[(size_t)h * nC + c0];
  const float n1v = cbn[(size_t)h * nC + c1];
  for (int rr = 0; rr < 8; ++rr) {
    float v0 = n0v - 2.f * acc0[rr];
    float v1 = n1v - 2.f * acc1[rr];
    float bv = v0; int bi = c0;
    if (v1 < v0) { bv = v1; bi = c1; }   // tie keeps lower index c0
    rv[tid] = bv; ri[tid] = bi;
    __syncthreads();
    for (int off = 128; off; off >>= 1) {
      if (tid < off) {
        float ov = rv[tid + off]; int oi2 = ri[tid + off];
        if (ov < rv[tid] || (ov == rv[tid] && oi2 < ri[tid])) { rv[tid] = ov; ri[tid] = oi2; }
      }
      __syncthreads();
    }
    if (tid == 0) { zsel[rr] = ri[0]; lsel[rr] = knorm[rr] + rv[0]; }
    __syncthreads();
  }
  {
    float4 cv = *(const float4*)(cb + ((size_t)h * nC + zsel[r]) * 128 + d4);
    *(float4*)(khat + ((size_t)((b * nT + t0 + r) * nH + h)) * 128 + d4) = cv;
  }
  if (tid == 0) {
    float s = 0.f;
#pragma unroll
    for (int rr = 0; rr < 8; ++rr) s += mask[b * nT + t0 + rr] * lsel[rr];
    blocksq[blockIdx.y * gridDim.x + blockIdx.x] = s;
  }
}

// ---------------- flash attention: 16 q-rows per block ----------------
__global__ __launch_bounds__(256) void attn_kernel(
    const float* __restrict__ qb, const float* __restrict__ khat,
    const float* __restrict__ vbuf, const float* __restrict__ xlk,
    const float* __restrict__ xlv, const float* __restrict__ cb,
    const float* __restrict__ aggU, const float* __restrict__ aggL,
    const float* __restrict__ g, float* __restrict__ o) {
  __shared__ float qs[16][132];
  __shared__ float ks[32][132];
  __shared__ float vs[32][132];
  __shared__ float wb[16][32];
  __shared__ float lowb[32];
  const int tid = threadIdx.x;
  const int b = blockIdx.y >> 3, h = blockIdx.y & 7;
  const int t0 = blockIdx.x * 16;
  {
    int qr = tid >> 4, qd = (tid & 15) * 8;
    const float* src = qb + ((size_t)((b * nT + t0 + qr) * nH + h)) * 128 + qd;
    *(float4*)&qs[qr][qd] = *(const float4*)src;
    *(float4*)&qs[qr][qd + 4] = *(const float4*)(src + 4);
  }
  const int r = tid >> 4, p = tid & 15;
  const int t = t0 + r;
  const int d0 = p * 8;
  const int kr = tid >> 3, f0 = (tid & 7) * 16;
  float mr = -1e30f, dr = 0.f;
  float num[8] = {0, 0, 0, 0, 0, 0, 0, 0};
  const int smax = nM + t0 + 15;

  for (int ci = 0; ci < (nM + nT) / 32; ++ci) {
    const int sbase = ci * 32;
    if (sbase > smax) break;      // block-uniform
    __syncthreads();
    {
      const int s = sbase + kr;
      const float *srck, *srcv;
      if (s < nM) {
        size_t idx = ((size_t)(b * nH + h) * nM + s) * 128 + f0;
        srck = xlk + idx; srcv = xlv + idx;
      } else {
        size_t idx = ((size_t)((b * nT + (s - nM)) * nH + h)) * 128 + f0;
        srck = khat + idx; srcv = vbuf + idx;
      }
#pragma unroll
      for (int q4 = 0; q4 < 4; ++q4) {
        *(float4*)&ks[kr][f0 + q4 * 4] = *(const float4*)(srck + q4 * 4);
        *(float4*)&vs[kr][f0 + q4 * 4] = *(const float4*)(srcv + q4 * 4);
      }
    }
    __syncthreads();
    float a0 = 0.f, a1 = 0.f;
#pragma unroll 8
    for (int i = 0; i < 32; ++i) {
      float4 qv = *(const float4*)&qs[r][i * 4];
      float4 k0 = *(const float4*)&ks[p][i * 4];
      float4 k1 = *(const float4*)&ks[p + 16][i * 4];
      a0 += qv.x * k0.x + qv.y * k0.y + qv.z * k0.z + qv.w * k0.w;
      a1 += qv.x * k1.x + qv.y * k1.y + qv.z * k1.z + qv.w * k1.w;
    }
    float s0 = a0 * RTAU, s1 = a1 * RTAU;
    if (sbase + p > t + nM) s0 = -1e30f;
    if (sbase + p + 16 > t + nM) s1 = -1e30f;
    float cm = fmaxf(s0, s1);
#pragma unroll
    for (int off = 1; off < 16; off <<= 1) cm = fmaxf(cm, __shfl_xor(cm, off));
    float mnew = fmaxf(mr, cm);
    float scale = __expf(mr - mnew);
    float w0 = __expf(s0 - mnew), w1 = __expf(s1 - mnew);
    wb[r][p] = w0; wb[r][p + 16] = w1;   // same-wave produce/consume
    float wsum = w0 + w1;
#pragma unroll
    for (int off = 1; off < 16; off <<= 1) wsum += __shfl_xor(wsum, off);
    dr = dr * scale + wsum;
    mr = mnew;
#pragma unroll
    for (int j = 0; j < 8; ++j) num[j] *= scale;
#pragma unroll 4
    for (int kx = 0; kx < 32; ++kx) {
      float w = wb[r][kx];
      float4 v0 = *(const float4*)&vs[kx][d0];
      float4 v1 = *(const float4*)&vs[kx][d0 + 4];
      num[0] += w * v0.x; num[1] += w * v0.y; num[2] += w * v0.z; num[3] += w * v0.w;
      num[4] += w * v1.x; num[5] += w * v1.y; num[6] += w * v1.z; num[7] += w * v1.w;
    }
  }

  for (int ca = 0; ca < nC / 32; ++ca) {
    __syncthreads();
    {
      const int c = ca * 32 + kr;
      const float* srck = cb + ((size_t)h * nC + c) * 128 + f0;
      const float* srcv = aggU + ((size_t)(b * nH + h) * nC + c) * 128 + f0;
#pragma unroll
      for (int q4 = 0; q4 < 4; ++q4) {
        *(float4*)&ks[kr][f0 + q4 * 4] = *(const float4*)(srck + q4 * 4);
        *(float4*)&vs[kr][f0 + q4 * 4] = *(const float4*)(srcv + q4 * 4);
      }
      if (tid < 32) lowb[tid] = aggL[(size_t)(b * nH + h) * nC + ca * 32 + tid];
    }
    __syncthreads();
    float a0 = 0.f, a1 = 0.f;
#pragma unroll 8
    for (int i = 0; i < 32; ++i) {
      float4 qv = *(const float4*)&qs[r][i * 4];
      float4 k0 = *(const float4*)&ks[p][i * 4];
      float4 k1 = *(const float4*)&ks[p + 16][i * 4];
      a0 += qv.x * k0.x + qv.y * k0.y + qv.z * k0.z + qv.w * k0.w;
      a1 += qv.x * k1.x + qv.y * k1.y + qv.z * k1.z + qv.w * k1.w;
    }
    float s0 = a0 * RTAU, s1 = a1 * RTAU;
    float cm = fmaxf(s0, s1);
#pragma unroll
    for (int off = 1; off < 16; off <<= 1) cm = fmaxf(cm, __shfl_xor(cm, off));
    float mnew = fmaxf(mr, cm);
    float scale = __expf(mr - mnew);
    float w0 = __expf(s0 - mnew), w1 = __expf(s1 - mnew);
    wb[r][p] = w0; wb[r][p + 16] = w1;
    float wsum = w0 * lowb[p] + w1 * lowb[p + 16];
#pragma unroll
    for (int off = 1; off < 16; off <<= 1) wsum += __shfl_xor(wsum, off);
    dr = dr * scale + wsum;
    mr = mnew;
#pragma unroll
    for (int j = 0; j < 8; ++j) num[j] *= scale;
#pragma unroll 4
    for (int kx = 0; kx < 32; ++kx) {
      float w = wb[r][kx];
      float4 v0 = *(const float4*)&vs[kx][d0];
      float4 v1 = *(const float4*)&vs[kx][d0 + 4];
      num[0] += w * v0.x; num[1] += w * v0.y; num[2] += w * v0.z; num[3] += w * v0.w;
      num[4] += w * v1.x; num[5] += w * v1.y; num[6] += w * v1.z; num[7] += w * v1.w;
    }
  }

  float inv = 1.f / dr;
  size_t oi = ((size_t)((b * nT + t) * nH + h)) * 128 + d0;
  float4 g0 = *(const float4*)(g + oi);
  float4 g1 = *(const float4*)(g + oi + 4);
  float4 o0 = make_float4(num[0] * inv * g0.x, num[1] * inv * g0.y,
                          num[2] * inv * g0.z, num[3] * inv * g0.w);
  float4 o1 = make_float4(num[4] * inv * g1.x, num[5] * inv * g1.y,
                          num[6] * inv * g1.z, num[7] * inv * g1.w);
  *(float4*)(o + oi) = o0;
  *(float4*)(o + oi + 4) = o1;
}

// ---------------- losses ----------------
__global__ __launch_bounds__(256) void finalize_kernel(const float* __restrict__ blocksq,
                                                       const float* __restrict__ mask,
                                                       float* __restrict__ outp) {
  __shared__ float sm[8];
  const int tid = threadIdx.x;
  float s = 0.f, ms = 0.f;
  for (int i = tid; i < NROW; i += 256) { s += blocksq[i]; ms += mask[i]; }
#pragma unroll
  for (int off = 32; off; off >>= 1) { s += __shfl_down(s, off); ms += __shfl_down(ms, off); }
  if ((tid & 63) == 0) { sm[tid >> 6] = s; sm[4 + (tid >> 6)] = ms; }
  __syncthreads();
  if (tid == 0) {
    float ts = sm[0] + sm[1] + sm[2] + sm[3];
    float tm = sm[4] + sm[5] + sm[6] + sm[7];
    float l = ts / (tm * (float)nH + 1e-6f);
    outp[0] = l;   // l_commit
    outp[1] = l;   // l_codebook (identical in forward)
  }
}

}  // namespace

extern "C" void kernel_launch(void* const* d_in, const int* in_sizes, int n_in,
                              void* d_out, int out_size, void* d_ws, size_t ws_size,
                              hipStream_t stream) {
  const float* x    = (const float*)d_in[0];
  // d_in[1] doc_ids: unused by the reference
  const float* mask = (const float*)d_in[2];
  const float* xlk  = (const float*)d_in[3];
  const float* xlv  = (const float*)d_in[4];
  const float* aggU = (const float*)d_in[5];
  const float* aggL = (const float*)d_in[6];
  const float* wlng = (const float*)d_in[7];
  const float* wlnb = (const float*)d_in[8];
  const float* wq   = (const float*)d_in[9];
  const float* wk   = (const float*)d_in[10];
  const float* wv   = (const float*)d_in[11];
  const float* wg   = (const float*)d_in[12];
  const float* wres = (const float*)d_in[13];
  const float* xu   = (const float*)d_in[14];
  const float* cb   = (const float*)d_in[15];
  float* out = (float*)d_out;

  float* ws = (float*)d_ws;
  const size_t SZ = (size_t)NROW * nD;   // 4M floats
  float* xt   = ws;            // also reused as obuf after projections
  float* qbuf = ws + SZ;
  float* kbuf = ws + 2 * SZ;
  float* vbuf = ws + 3 * SZ;
  float* gbuf = ws + 4 * SZ;
  float* khat = ws + 5 * SZ;
  float* cbT  = ws + 6 * SZ;                 // 524288
  float* cbn  = cbT + (size_t)nH * nC * 128; // 4096
  float* bsq  = cbn + (size_t)nH * nC;       // 4096
  float* obuf = xt;  // xt dead after the 4 projection GEMMs

  ln_kernel<<<NROW, 256, 0, stream>>>(x, wlng, wlnb, xt);
  cbprep_kernel<<<nH * nC, 128, 0, stream>>>(cb, cbT, cbn);

  dim3 ggrid(nD / 64, NROW / 128);
  gemm_kernel<0><<<ggrid, 256, 0, stream>>>(xt, wq, qbuf);
  gemm_kernel<0><<<ggrid, 256, 0, stream>>>(xt, wk, kbuf);
  gemm_kernel<0><<<ggrid, 256, 0, stream>>>(xt, wv, vbuf);
  gemm_kernel<1><<<ggrid, 256, 0, stream>>>(xt, wg, gbuf);

  hln_kernel<1><<<(NROW * nH) / 4, 256, 0, stream>>>(qbuf, xu);
  hln_kernel<0><<<(NROW * nH) / 4, 256, 0, stream>>>(kbuf, nullptr);

  vq_kernel<<<dim3(nT / 8, nB * nH), 256, 0, stream>>>(kbuf, cb, cbT, cbn, mask, khat, bsq);

  attn_kernel<<<dim3(nT / 16, nB * nH), 256, 0, stream>>>(qbuf, khat, vbuf, xlk, xlv,
                                                          cb, aggU, aggL, gbuf, obuf);

  gemm_kernel<0><<<ggrid, 256, 0, stream>>>(obuf, wres, out);
  finalize_kernel<<<1, 256, 0, stream>>>(bsq, mask, out + SZ);
}

// Round 4
// 857.236 us; speedup vs baseline: 1.8429x; 1.8429x over previous
//
#include <hip/hip_runtime.h>
#include <math.h>

namespace {

constexpr int nB = 8, nT = 512, nD = 1024, nH = 8, nDK = 128, nDV = 128, nC = 512, nM = 512;
constexpr int NROW = nB * nT;                  // 4096
constexpr float RTAU = 0.08838834764831845f;   // 1/sqrt(128)

typedef __attribute__((ext_vector_type(8))) short short8;
typedef __attribute__((ext_vector_type(4))) float f32x4;

__device__ __forceinline__ ushort f2bf(float f) {
  union { float f; uint u; } x; x.f = f;
  uint r = x.u + 0x7fff + ((x.u >> 16) & 1);
  return (ushort)(r >> 16);
}
__device__ __forceinline__ uint pk2(float a, float b) {
  return (uint)f2bf(a) | ((uint)f2bf(b) << 16);
}

__device__ __forceinline__ float blockReduce256(float v, float* sm) {
  int lane = threadIdx.x & 63, w = threadIdx.x >> 6;
#pragma unroll
  for (int off = 32; off; off >>= 1) v += __shfl_down(v, off);
  if (lane == 0) sm[w] = v;
  __syncthreads();
  float r = sm[0] + sm[1] + sm[2] + sm[3];
  __syncthreads();
  return r;
}

// ---------------- LayerNorm over D=1024, one block per (b,t) row ----------------
__global__ __launch_bounds__(256) void ln_kernel(const float* __restrict__ x,
                                                 const float* __restrict__ gw,
                                                 const float* __restrict__ bw,
                                                 float* __restrict__ xt) {
  __shared__ float sm[4];
  size_t row = blockIdx.x;
  float4 v = ((const float4*)(x + row * nD))[threadIdx.x];
  float mu = blockReduce256(v.x + v.y + v.z + v.w, sm) * (1.f / nD);
  float4 d = make_float4(v.x - mu, v.y - mu, v.z - mu, v.w - mu);
  float var = blockReduce256(d.x * d.x + d.y * d.y + d.z * d.z + d.w * d.w, sm) * (1.f / nD);
  float rs = rsqrtf(var + 1e-6f);
  float4 gg = ((const float4*)gw)[threadIdx.x];
  float4 bb = ((const float4*)bw)[threadIdx.x];
  float4 o = make_float4(d.x * rs * gg.x + bb.x, d.y * rs * gg.y + bb.y,
                         d.z * rs * gg.z + bb.z, d.w * rs * gg.w + bb.w);
  ((float4*)(xt + row * nD))[threadIdx.x] = o;
}

// ---------------- fp32 tiled GEMM ----------------
template <int ACT>
__global__ __launch_bounds__(256) void gemm_kernel(const float* __restrict__ A,
                                                   const float* __restrict__ W,
                                                   float* __restrict__ Cp) {
  __shared__ float As[16][132];
  __shared__ float Bs[16][68];
  const int tid = threadIdx.x;
  const int m0 = blockIdx.x * 64;
  const int n0 = blockIdx.y * 128;
  const int tx = tid & 15, ty = tid >> 4;
  const int ai = tid >> 1, ak = (tid & 1) * 8;
  const int bk = tid >> 4, bj = (tid & 15) * 4;
  float acc[8][4];
#pragma unroll
  for (int i = 0; i < 8; ++i)
#pragma unroll
    for (int j = 0; j < 4; ++j) acc[i][j] = 0.f;

  for (int k0 = 0; k0 < nD; k0 += 16) {
    float4 a0 = *(const float4*)(A + (size_t)(n0 + ai) * nD + k0 + ak);
    float4 a1 = *(const float4*)(A + (size_t)(n0 + ai) * nD + k0 + ak + 4);
    float4 b4 = *(const float4*)(W + (size_t)(k0 + bk) * nD + m0 + bj);
    As[ak + 0][ai] = a0.x; As[ak + 1][ai] = a0.y; As[ak + 2][ai] = a0.z; As[ak + 3][ai] = a0.w;
    As[ak + 4][ai] = a1.x; As[ak + 5][ai] = a1.y; As[ak + 6][ai] = a1.z; As[ak + 7][ai] = a1.w;
    *(float4*)&Bs[bk][bj] = b4;
    __syncthreads();
#pragma unroll
    for (int kk = 0; kk < 16; ++kk) {
      float4 av0 = *(const float4*)&As[kk][ty * 8];
      float4 av1 = *(const float4*)&As[kk][ty * 8 + 4];
      float4 bv = *(const float4*)&Bs[kk][tx * 4];
      float a8[8] = {av0.x, av0.y, av0.z, av0.w, av1.x, av1.y, av1.z, av1.w};
      float b4a[4] = {bv.x, bv.y, bv.z, bv.w};
#pragma unroll
      for (int i = 0; i < 8; ++i)
#pragma unroll
        for (int j = 0; j < 4; ++j) acc[i][j] += a8[i] * b4a[j];
    }
    __syncthreads();
  }
#pragma unroll
  for (int i = 0; i < 8; ++i) {
    float4 o = make_float4(acc[i][0], acc[i][1], acc[i][2], acc[i][3]);
    if (ACT == 1) {
      o.x = o.x / (1.f + __expf(-o.x));
      o.y = o.y / (1.f + __expf(-o.y));
      o.z = o.z / (1.f + __expf(-o.z));
      o.w = o.w / (1.f + __expf(-o.w));
    }
    *(float4*)(Cp + (size_t)(n0 + ty * 8 + i) * nD + m0 + tx * 4) = o;
  }
}

// ---------------- headwise LN over 128 ----------------
template <int ADDXU>
__global__ __launch_bounds__(256) void hln_kernel(float* __restrict__ buf,
                                                  const float* __restrict__ xu) {
  int lane = threadIdx.x & 63;
  size_t row = (size_t)blockIdx.x * 4 + (threadIdx.x >> 6);
  float* p = buf + row * 128;
  float2 v = *(float2*)(p + lane * 2);
  float s = v.x + v.y;
#pragma unroll
  for (int off = 32; off; off >>= 1) s += __shfl_down(s, off);
  float mu = __shfl(s, 0) * (1.f / 128.f);
  float dx = v.x - mu, dy = v.y - mu;
  float q = dx * dx + dy * dy;
#pragma unroll
  for (int off = 32; off; off >>= 1) q += __shfl_down(q, off);
  float rs = rsqrtf(__shfl(q, 0) * (1.f / 128.f) + 1e-6f);
  float ox = dx * rs, oy = dy * rs;
  if (ADDXU) {
    int h = (int)(row & 7);
    ox += xu[h * 128 + lane * 2];
    oy += xu[h * 128 + lane * 2 + 1];
  }
  *(float2*)(p + lane * 2) = make_float2(ox, oy);
}

// ---------------- codebook transpose + norms ----------------
__global__ __launch_bounds__(128) void cbprep_kernel(const float* __restrict__ cb,
                                                     float* __restrict__ cbT,
                                                     float* __restrict__ cbn) {
  __shared__ float sm[2];
  const int hc = blockIdx.x;
  const int h = hc >> 9, c = hc & 511;
  float v = cb[(size_t)hc * 128 + threadIdx.x];
  cbT[((size_t)h * 128 + threadIdx.x) * nC + c] = v;
  float s = v * v;
#pragma unroll
  for (int off = 32; off; off >>= 1) s += __shfl_down(s, off);
  if ((threadIdx.x & 63) == 0) sm[threadIdx.x >> 6] = s;
  __syncthreads();
  if (threadIdx.x == 0) cbn[hc] = sm[0] + sm[1];
}

// ---------------- VQ argmin + loss partials ----------------
__global__ __launch_bounds__(256) void vq_kernel(const float* __restrict__ kbuf,
                                                 const float* __restrict__ cb,
                                                 const float* __restrict__ cbT,
                                                 const float* __restrict__ cbn,
                                                 const float* __restrict__ mask,
                                                 float* __restrict__ khat,
                                                 float* __restrict__ blocksq) {
  __shared__ float ksh[8][128];
  __shared__ float knorm[8];
  __shared__ float rv[256];
  __shared__ int ri[256];
  __shared__ int zsel[8];
  __shared__ float lsel[8];
  const int tid = threadIdx.x;
  const int b = blockIdx.y >> 3, h = blockIdx.y & 7;
  const int t0 = blockIdx.x * 8;
  const int r = tid >> 5, d4 = (tid & 31) * 4;
  {
    const float* kr = kbuf + ((size_t)((b * nT + t0 + r) * nH + h)) * 128 + d4;
    float4 kv = *(const float4*)kr;
    *(float4*)&ksh[r][d4] = kv;
    float sq = kv.x * kv.x + kv.y * kv.y + kv.z * kv.z + kv.w * kv.w;
#pragma unroll
    for (int off = 16; off; off >>= 1) sq += __shfl_down(sq, off, 32);
    if ((tid & 31) == 0) knorm[r] = sq;
  }
  __syncthreads();
  const int c0 = tid, c1 = tid + 256;
  float acc0[8], acc1[8];
#pragma unroll
  for (int i = 0; i < 8; ++i) { acc0[i] = 0.f; acc1[i] = 0.f; }
  const float* cbTh = cbT + (size_t)h * 128 * nC;
#pragma unroll 2
  for (int d = 0; d < 128; ++d) {
    float w0 = cbTh[(size_t)d * nC + c0];
    float w1 = cbTh[(size_t)d * nC + c1];
#pragma unroll
    for (int rr = 0; rr < 8; ++rr) {
      float kv = ksh[rr][d];
      acc0[rr] += kv * w0;
      acc1[rr] += kv * w1;
    }
  }
  const float n0v = cbn[(size_t)h * nC + c0];
  const float n1v = cbn[(size_t)h * nC + c1];
  for (int rr = 0; rr < 8; ++rr) {
    float v0 = n0v - 2.f * acc0[rr];
    float v1 = n1v - 2.f * acc1[rr];
    float bv = v0; int bi = c0;
    if (v1 < v0) { bv = v1; bi = c1; }
    rv[tid] = bv; ri[tid] = bi;
    __syncthreads();
    for (int off = 128; off; off >>= 1) {
      if (tid < off) {
        float ov = rv[tid + off]; int oi2 = ri[tid + off];
        if (ov < rv[tid] || (ov == rv[tid] && oi2 < ri[tid])) { rv[tid] = ov; ri[tid] = oi2; }
      }
      __syncthreads();
    }
    if (tid == 0) { zsel[rr] = ri[0]; lsel[rr] = knorm[rr] + rv[0]; }
    __syncthreads();
  }
  {
    float4 cv = *(const float4*)(cb + ((size_t)h * nC + zsel[r]) * 128 + d4);
    *(float4*)(khat + ((size_t)((b * nT + t0 + r) * nH + h)) * 128 + d4) = cv;
  }
  if (tid == 0) {
    float s = 0.f;
#pragma unroll
    for (int rr = 0; rr < 8; ++rr) s += mask[b * nT + t0 + rr] * lsel[rr];
    blocksq[blockIdx.y * gridDim.x + blockIdx.x] = s;
  }
}

// ---------------- MFMA flash attention ----------------
// block = 256 thr = 4 waves; block handles (b, h, 64 q-rows); wave w owns rows [w*16, w*16+16)
// chunk = 64 keys. K in LDS row-major bf16 [64][136]; V transposed [128][72]; per-wave P [16][72].
__global__ __launch_bounds__(256) void attn_mfma_kernel(
    const float* __restrict__ qb, const float* __restrict__ khat,
    const float* __restrict__ vbuf, const float* __restrict__ xlk,
    const float* __restrict__ xlv, const float* __restrict__ cb,
    const float* __restrict__ aggU, const float* __restrict__ aggL,
    const float* __restrict__ gbuf, float* __restrict__ o) {
  __shared__ ushort Ks[64][136];
  __shared__ ushort Vts[128][72];
  __shared__ ushort Ps[4][16][72];
  __shared__ float lowb[64];

  const int tid = threadIdx.x;
  const int w = tid >> 6, l = tid & 63;
  const int lr = l & 15, lg = l >> 4;
  const int b = blockIdx.y >> 3, h = blockIdx.y & 7;
  const int t0 = blockIdx.x * 64;

  // Q fragments (held in registers for the whole kernel)
  short8 qf[4];
  {
    const float* qrow = qb + ((size_t)((b * nT + t0 + w * 16 + lr) * nH + h)) * 128;
#pragma unroll
    for (int k0 = 0; k0 < 4; ++k0) {
      float4 a = *(const float4*)(qrow + k0 * 32 + lg * 8);
      float4 c = *(const float4*)(qrow + k0 * 32 + lg * 8 + 4);
      union { short8 v; uint u[4]; } t;
      t.u[0] = pk2(a.x, a.y); t.u[1] = pk2(a.z, a.w);
      t.u[2] = pk2(c.x, c.y); t.u[3] = pk2(c.z, c.w);
      qf[k0] = t.v;
    }
  }

  float m_r[4] = {-1e30f, -1e30f, -1e30f, -1e30f};
  float l_r[4] = {0.f, 0.f, 0.f, 0.f};
  f32x4 acc_o[8];
#pragma unroll
  for (int dt = 0; dt < 8; ++dt) acc_o[dt] = (f32x4){0.f, 0.f, 0.f, 0.f};

  const int srow = tid >> 2, sd = (tid & 3) * 32;     // K staging: 4 thr/row
  const int kp = tid & 31, dbase = (tid >> 5) * 16;   // V staging: key-pair + 16 d's

  // stage 32 floats -> 32 bf16 into Ks[srow][sd..]
  auto stageK = [&](const float* src) {
#pragma unroll
    for (int q4 = 0; q4 < 4; ++q4) {
      float4 a = *(const float4*)(src + q4 * 8);
      float4 c = *(const float4*)(src + q4 * 8 + 4);
      uint4 wv;
      wv.x = pk2(a.x, a.y); wv.y = pk2(a.z, a.w);
      wv.z = pk2(c.x, c.y); wv.w = pk2(c.z, c.w);
      *(uint4*)&Ks[srow][sd + q4 * 8] = wv;
    }
  };
  // stage V rows s0, s0+1 transposed into Vts
  auto stageV = [&](const float* v0, const float* v1) {
    float4 r0[4], r1[4];
#pragma unroll
    for (int i2 = 0; i2 < 4; ++i2) {
      r0[i2] = *(const float4*)(v0 + i2 * 4);
      r1[i2] = *(const float4*)(v1 + i2 * 4);
    }
#pragma unroll
    for (int i2 = 0; i2 < 16; ++i2) {
      float a = ((const float*)r0)[i2], c = ((const float*)r1)[i2];
      *(uint*)&Vts[dbase + i2][2 * kp] = pk2(a, c);
    }
  };

  auto chunk_body = [&](int sbase, bool AGG, bool MASKQ) {
    // ---- S = Q K^T (4 key-tiles of 16) ----
    f32x4 sc[4];
#pragma unroll
    for (int kt = 0; kt < 4; ++kt) {
      f32x4 z = (f32x4){0.f, 0.f, 0.f, 0.f};
#pragma unroll
      for (int k0 = 0; k0 < 4; ++k0) {
        short8 kf = *(const short8*)&Ks[kt * 16 + lr][k0 * 32 + lg * 8];
        z = __builtin_amdgcn_mfma_f32_16x16x32_bf16(qf[k0], kf, z, 0, 0, 0);
      }
      sc[kt] = z;
    }
    // ---- online softmax (rows = lg*4+r2, cols = kt*16+lr) ----
    float sv[4][4];
    float pm[4] = {-1e30f, -1e30f, -1e30f, -1e30f};
#pragma unroll
    for (int kt = 0; kt < 4; ++kt)
#pragma unroll
      for (int r2 = 0; r2 < 4; ++r2) {
        float s = sc[kt][r2] * RTAU;
        if (MASKQ) {
          int key = sbase + kt * 16 + lr;
          int tl = t0 + w * 16 + lg * 4 + r2 + nM;
          if (key > tl) s = -1e30f;
        }
        sv[kt][r2] = s;
        pm[r2] = fmaxf(pm[r2], s);
      }
#pragma unroll
    for (int r2 = 0; r2 < 4; ++r2)
#pragma unroll
      for (int off = 1; off < 16; off <<= 1) pm[r2] = fmaxf(pm[r2], __shfl_xor(pm[r2], off));
    float scale[4], rs[4];
#pragma unroll
    for (int r2 = 0; r2 < 4; ++r2) {
      float mn = fmaxf(m_r[r2], pm[r2]);
      scale[r2] = __expf(m_r[r2] - mn);
      m_r[r2] = mn;
      rs[r2] = 0.f;
    }
#pragma unroll
    for (int kt = 0; kt < 4; ++kt)
#pragma unroll
      for (int r2 = 0; r2 < 4; ++r2) {
        float p = __expf(sv[kt][r2] - m_r[r2]);
        rs[r2] += AGG ? p * lowb[kt * 16 + lr] : p;
        Ps[w][lg * 4 + r2][kt * 16 + lr] = f2bf(p);   // unweighted P for numerator
      }
#pragma unroll
    for (int r2 = 0; r2 < 4; ++r2)
#pragma unroll
      for (int off = 1; off < 16; off <<= 1) rs[r2] += __shfl_xor(rs[r2], off);
#pragma unroll
    for (int r2 = 0; r2 < 4; ++r2) l_r[r2] = l_r[r2] * scale[r2] + rs[r2];
#pragma unroll
    for (int dt = 0; dt < 8; ++dt)
#pragma unroll
      for (int r2 = 0; r2 < 4; ++r2) acc_o[dt][r2] *= scale[r2];
    // ---- O += P V (same-wave LDS round-trip, DS is in-order per wave) ----
    short8 pa0 = *(const short8*)&Ps[w][lr][lg * 8];
    short8 pa1 = *(const short8*)&Ps[w][lr][32 + lg * 8];
#pragma unroll
    for (int dt = 0; dt < 8; ++dt) {
      short8 vf0 = *(const short8*)&Vts[dt * 16 + lr][lg * 8];
      short8 vf1 = *(const short8*)&Vts[dt * 16 + lr][32 + lg * 8];
      acc_o[dt] = __builtin_amdgcn_mfma_f32_16x16x32_bf16(pa0, vf0, acc_o[dt], 0, 0, 0);
      acc_o[dt] = __builtin_amdgcn_mfma_f32_16x16x32_bf16(pa1, vf1, acc_o[dt], 0, 0, 0);
    }
  };

  // ---- recent phase: keys [0, M + t0 + 64), only last chunk needs the causal mask ----
  const int nch = t0 / 64 + 9;
  for (int ci = 0; ci < nch; ++ci) {
    const int sbase = ci * 64;
    __syncthreads();
    {
      int s = sbase + srow;
      const float* src = (s < nM)
          ? xlk + ((size_t)(b * nH + h) * nM + s) * 128 + sd
          : khat + ((size_t)((b * nT + (s - nM)) * nH + h)) * 128 + sd;
      stageK(src);
    }
    {
      int s0 = sbase + 2 * kp;
      if (s0 < nM) {
        const float* v0 = xlv + ((size_t)(b * nH + h) * nM + s0) * 128 + dbase;
        stageV(v0, v0 + 128);
      } else {
        const float* v0 = vbuf + ((size_t)((b * nT + (s0 - nM)) * nH + h)) * 128 + dbase;
        stageV(v0, v0 + nH * 128);
      }
    }
    __syncthreads();
    chunk_body(sbase, false, ci == nch - 1);
  }

  // ---- aggregate phase: 512 codebook keys, aggU values, aggL-weighted denominator ----
  for (int ca = 0; ca < 8; ++ca) {
    const int sbase = ca * 64;
    __syncthreads();
    stageK(cb + ((size_t)h * nC + sbase + srow) * 128 + sd);
    {
      const float* v0 = aggU + ((size_t)(b * nH + h) * nC + sbase + 2 * kp) * 128 + dbase;
      stageV(v0, v0 + 128);
    }
    if (tid < 64) lowb[tid] = aggL[(size_t)(b * nH + h) * nC + sbase + tid];
    __syncthreads();
    chunk_body(sbase, true, false);
  }

  // ---- epilogue: wv = O/den, multiply by g, write (B,T,H*DV) ----
  float inv[4];
#pragma unroll
  for (int r2 = 0; r2 < 4; ++r2) inv[r2] = 1.f / l_r[r2];
#pragma unroll
  for (int dt = 0; dt < 8; ++dt)
#pragma unroll
    for (int r2 = 0; r2 < 4; ++r2) {
      int trow = t0 + w * 16 + lg * 4 + r2;
      size_t oi = ((size_t)(b * nT + trow)) * nD + h * 128 + dt * 16 + lr;
      o[oi] = acc_o[dt][r2] * inv[r2] * gbuf[oi];
    }
}

// ---------------- losses ----------------
__global__ __launch_bounds__(256) void finalize_kernel(const float* __restrict__ blocksq,
                                                       const float* __restrict__ mask,
                                                       float* __restrict__ outp) {
  __shared__ float sm[8];
  const int tid = threadIdx.x;
  float s = 0.f, ms = 0.f;
  for (int i = tid; i < NROW; i += 256) { s += blocksq[i]; ms += mask[i]; }
#pragma unroll
  for (int off = 32; off; off >>= 1) { s += __shfl_down(s, off); ms += __shfl_down(ms, off); }
  if ((tid & 63) == 0) { sm[tid >> 6] = s; sm[4 + (tid >> 6)] = ms; }
  __syncthreads();
  if (tid == 0) {
    float ts = sm[0] + sm[1] + sm[2] + sm[3];
    float tm = sm[4] + sm[5] + sm[6] + sm[7];
    float l = ts / (tm * (float)nH + 1e-6f);
    outp[0] = l;
    outp[1] = l;
  }
}

}  // namespace

extern "C" void kernel_launch(void* const* d_in, const int* in_sizes, int n_in,
                              void* d_out, int out_size, void* d_ws, size_t ws_size,
                              hipStream_t stream) {
  const float* x    = (const float*)d_in[0];
  const float* mask = (const float*)d_in[2];
  const float* xlk  = (const float*)d_in[3];
  const float* xlv  = (const float*)d_in[4];
  const float* aggU = (const float*)d_in[5];
  const float* aggL = (const float*)d_in[6];
  const float* wlng = (const float*)d_in[7];
  const float* wlnb = (const float*)d_in[8];
  const float* wq   = (const float*)d_in[9];
  const float* wk   = (const float*)d_in[10];
  const float* wv   = (const float*)d_in[11];
  const float* wg   = (const float*)d_in[12];
  const float* wres = (const float*)d_in[13];
  const float* xu   = (const float*)d_in[14];
  const float* cb   = (const float*)d_in[15];
  float* out = (float*)d_out;

  float* ws = (float*)d_ws;
  const size_t SZ = (size_t)NROW * nD;
  float* xt   = ws;
  float* qbuf = ws + SZ;
  float* kbuf = ws + 2 * SZ;
  float* vbuf = ws + 3 * SZ;
  float* gbuf = ws + 4 * SZ;
  float* khat = ws + 5 * SZ;
  float* cbT  = ws + 6 * SZ;
  float* cbn  = cbT + (size_t)nH * nC * 128;
  float* bsq  = cbn + (size_t)nH * nC;
  float* obuf = xt;  // xt dead after projections

  ln_kernel<<<NROW, 256, 0, stream>>>(x, wlng, wlnb, xt);
  cbprep_kernel<<<nH * nC, 128, 0, stream>>>(cb, cbT, cbn);

  dim3 ggrid(nD / 64, NROW / 128);
  gemm_kernel<0><<<ggrid, 256, 0, stream>>>(xt, wq, qbuf);
  gemm_kernel<0><<<ggrid, 256, 0, stream>>>(xt, wk, kbuf);
  gemm_kernel<0><<<ggrid, 256, 0, stream>>>(xt, wv, vbuf);
  gemm_kernel<1><<<ggrid, 256, 0, stream>>>(xt, wg, gbuf);

  hln_kernel<1><<<(NROW * nH) / 4, 256, 0, stream>>>(qbuf, xu);
  hln_kernel<0><<<(NROW * nH) / 4, 256, 0, stream>>>(kbuf, nullptr);

  vq_kernel<<<dim3(nT / 8, nB * nH), 256, 0, stream>>>(kbuf, cb, cbT, cbn, mask, khat, bsq);

  attn_mfma_kernel<<<dim3(nT / 64, nB * nH), 256, 0, stream>>>(
      qbuf, khat, vbuf, xlk, xlv, cb, aggU, aggL, gbuf, obuf);

  gemm_kernel<0><<<ggrid, 256, 0, stream>>>(obuf, wres, out);
  finalize_kernel<<<1, 256, 0, stream>>>(bsq, mask, out + SZ);
}

// Round 5
// 458.683 us; speedup vs baseline: 3.4441x; 1.8689x over previous
//
#include <hip/hip_runtime.h>
#include <math.h>

namespace {

constexpr int nB = 8, nT = 512, nD = 1024, nH = 8, nDK = 128, nDV = 128, nC = 512, nM = 512;
constexpr int NROW = nB * nT;                  // 4096
constexpr float RTAU = 0.08838834764831845f;   // 1/sqrt(128)

typedef __attribute__((ext_vector_type(8))) short short8;
typedef __attribute__((ext_vector_type(4))) float f32x4;

__device__ __forceinline__ ushort f2bf(float f) {
  union { float f; uint u; } x; x.f = f;
  uint r = x.u + 0x7fff + ((x.u >> 16) & 1);
  return (ushort)(r >> 16);
}
__device__ __forceinline__ uint pk2(float a, float b) {
  return (uint)f2bf(a) | ((uint)f2bf(b) << 16);
}
__device__ __forceinline__ float bf2f(ushort u) {
  return __uint_as_float(((uint)u) << 16);
}
__device__ __forceinline__ void gload16(const void* g, void* l) {
  __builtin_amdgcn_global_load_lds((const __attribute__((address_space(1))) void*)g,
                                   (__attribute__((address_space(3))) void*)l, 16, 0, 0);
}

__device__ __forceinline__ float blockReduce256(float v, float* sm) {
  int lane = threadIdx.x & 63, w = threadIdx.x >> 6;
#pragma unroll
  for (int off = 32; off; off >>= 1) v += __shfl_down(v, off);
  if (lane == 0) sm[w] = v;
  __syncthreads();
  float r = sm[0] + sm[1] + sm[2] + sm[3];
  __syncthreads();
  return r;
}

// ---------------- LayerNorm: writes fp32 xt and bf16 xt_bf ----------------
__global__ __launch_bounds__(256) void ln_kernel(const float* __restrict__ x,
                                                 const float* __restrict__ gw,
                                                 const float* __restrict__ bw,
                                                 float* __restrict__ xt,
                                                 ushort* __restrict__ xt_bf) {
  __shared__ float sm[4];
  size_t row = blockIdx.x;
  float4 v = ((const float4*)(x + row * nD))[threadIdx.x];
  float mu = blockReduce256(v.x + v.y + v.z + v.w, sm) * (1.f / nD);
  float4 d = make_float4(v.x - mu, v.y - mu, v.z - mu, v.w - mu);
  float var = blockReduce256(d.x * d.x + d.y * d.y + d.z * d.z + d.w * d.w, sm) * (1.f / nD);
  float rs = rsqrtf(var + 1e-6f);
  float4 gg = ((const float4*)gw)[threadIdx.x];
  float4 bb = ((const float4*)bw)[threadIdx.x];
  float4 o = make_float4(d.x * rs * gg.x + bb.x, d.y * rs * gg.y + bb.y,
                         d.z * rs * gg.z + bb.z, d.w * rs * gg.w + bb.w);
  ((float4*)(xt + row * nD))[threadIdx.x] = o;
  uint2 pb;
  pb.x = pk2(o.x, o.y);
  pb.y = pk2(o.z, o.w);
  ((uint2*)(xt_bf + row * nD))[threadIdx.x] = pb;
}

// ---------------- weight transpose + bf16: D[n][k] = bf16(W[k][n]) ----------------
__global__ __launch_bounds__(256) void wtrans_kernel(const float* __restrict__ wq,
                                                     const float* __restrict__ wv,
                                                     const float* __restrict__ wg,
                                                     const float* __restrict__ wres,
                                                     ushort* __restrict__ wqvg_t,
                                                     ushort* __restrict__ wres_t) {
  __shared__ float tile[64][65];
  const int kz = blockIdx.x * 64;
  const int nz = blockIdx.y * 64;
  const float* W;
  ushort* D;
  if (blockIdx.z == 0)      { W = wq;   D = wqvg_t; }
  else if (blockIdx.z == 1) { W = wv;   D = wqvg_t + (size_t)1024 * 1024; }
  else if (blockIdx.z == 2) { W = wg;   D = wqvg_t + (size_t)2048 * 1024; }
  else                      { W = wres; D = wres_t; }
  const int c = threadIdx.x & 63, r4 = threadIdx.x >> 6;
#pragma unroll
  for (int i = 0; i < 16; ++i) {
    int r = i * 4 + r4;
    tile[r][c] = W[(size_t)(kz + r) * 1024 + nz + c];
  }
  __syncthreads();
#pragma unroll
  for (int i = 0; i < 16; ++i) {
    int n = i * 4 + r4;
    D[(size_t)(nz + n) * 1024 + kz + c] = f2bf(tile[c][n]);
  }
}

// ---------------- fp32 tiled GEMM (k-projection only: exact argmin path) ----------------
template <int ACT>
__global__ __launch_bounds__(256) void gemm_kernel(const float* __restrict__ A,
                                                   const float* __restrict__ W,
                                                   float* __restrict__ Cp) {
  __shared__ float As[16][132];
  __shared__ float Bs[16][68];
  const int tid = threadIdx.x;
  const int m0 = blockIdx.x * 64;
  const int n0 = blockIdx.y * 128;
  const int tx = tid & 15, ty = tid >> 4;
  const int ai = tid >> 1, ak = (tid & 1) * 8;
  const int bk = tid >> 4, bj = (tid & 15) * 4;
  float acc[8][4];
#pragma unroll
  for (int i = 0; i < 8; ++i)
#pragma unroll
    for (int j = 0; j < 4; ++j) acc[i][j] = 0.f;

  for (int k0 = 0; k0 < nD; k0 += 16) {
    float4 a0 = *(const float4*)(A + (size_t)(n0 + ai) * nD + k0 + ak);
    float4 a1 = *(const float4*)(A + (size_t)(n0 + ai) * nD + k0 + ak + 4);
    float4 b4 = *(const float4*)(W + (size_t)(k0 + bk) * nD + m0 + bj);
    As[ak + 0][ai] = a0.x; As[ak + 1][ai] = a0.y; As[ak + 2][ai] = a0.z; As[ak + 3][ai] = a0.w;
    As[ak + 4][ai] = a1.x; As[ak + 5][ai] = a1.y; As[ak + 6][ai] = a1.z; As[ak + 7][ai] = a1.w;
    *(float4*)&Bs[bk][bj] = b4;
    __syncthreads();
#pragma unroll
    for (int kk = 0; kk < 16; ++kk) {
      float4 av0 = *(const float4*)&As[kk][ty * 8];
      float4 av1 = *(const float4*)&As[kk][ty * 8 + 4];
      float4 bv = *(const float4*)&Bs[kk][tx * 4];
      float a8[8] = {av0.x, av0.y, av0.z, av0.w, av1.x, av1.y, av1.z, av1.w};
      float b4a[4] = {bv.x, bv.y, bv.z, bv.w};
#pragma unroll
      for (int i = 0; i < 8; ++i)
#pragma unroll
        for (int j = 0; j < 4; ++j) acc[i][j] += a8[i] * b4a[j];
    }
    __syncthreads();
  }
#pragma unroll
  for (int i = 0; i < 8; ++i) {
    float4 o = make_float4(acc[i][0], acc[i][1], acc[i][2], acc[i][3]);
    if (ACT == 1) {
      o.x = o.x / (1.f + __expf(-o.x));
      o.y = o.y / (1.f + __expf(-o.y));
      o.z = o.z / (1.f + __expf(-o.z));
      o.w = o.w / (1.f + __expf(-o.w));
    }
    *(float4*)(Cp + (size_t)(n0 + ty * 8 + i) * nD + m0 + tx * 4) = o;
  }
}

// ---------------- bf16 MFMA GEMM (m97 structure: 128x128 tile, BK=32) ----------------
// A: [M][1024] bf16 row-major.  Bt: [N][1024] bf16 row-major (pre-transposed weight).
// MODE 0: C fp32 -> Cq[row*1024 + n0+col]
// MODE 1 (fused qvg, N=3072): n<1024 -> Cq fp32; n<2048 -> Cv bf16; else silu -> Cg bf16
template <int MODE>
__global__ __launch_bounds__(256) void gemm_bf16_kernel(const ushort* __restrict__ A,
                                                        const ushort* __restrict__ Bt,
                                                        float* __restrict__ Cq,
                                                        ushort* __restrict__ Cv,
                                                        ushort* __restrict__ Cg) {
  __shared__ __align__(16) ushort As[128 * 32];
  __shared__ __align__(16) ushort Bs[128 * 32];
  const int tid = threadIdx.x;
  const int w = tid >> 6, l = tid & 63;
  const int lr = l & 15, lg = l >> 4;
  const int wr = w >> 1, wc = w & 1;
  const int n0 = blockIdx.x * 128;
  const int m0 = blockIdx.y * 128;
  constexpr int K = 1024;

  f32x4 acc[4][4];
#pragma unroll
  for (int i = 0; i < 4; ++i)
#pragma unroll
    for (int j = 0; j < 4; ++j) acc[i][j] = (f32x4){0.f, 0.f, 0.f, 0.f};

  // staging: tile [128][32] row-major, 2 rounds x 256 thr x 16B
  const int e0 = w * 512 + l * 8;
  const int r0 = e0 >> 5, c0 = e0 & 31;
  const int e1 = 2048 + e0;
  const int r1 = e1 >> 5, c1 = e1 & 31;
  const ushort* a0p = A + (size_t)(m0 + r0) * K + c0;
  const ushort* a1p = A + (size_t)(m0 + r1) * K + c1;
  const ushort* b0p = Bt + (size_t)(n0 + r0) * K + c0;
  const ushort* b1p = Bt + (size_t)(n0 + r1) * K + c1;
  ushort* lA0 = &As[w * 512];
  ushort* lA1 = &As[2048 + w * 512];
  ushort* lB0 = &Bs[w * 512];
  ushort* lB1 = &Bs[2048 + w * 512];

  for (int k0 = 0; k0 < K; k0 += 32) {
    __syncthreads();
    gload16(a0p + k0, lA0);
    gload16(a1p + k0, lA1);
    gload16(b0p + k0, lB0);
    gload16(b1p + k0, lB1);
    __syncthreads();
    short8 af[4], bfr[4];
#pragma unroll
    for (int i = 0; i < 4; ++i) af[i] = *(const short8*)&As[(wr * 64 + i * 16 + lr) * 32 + lg * 8];
#pragma unroll
    for (int j = 0; j < 4; ++j) bfr[j] = *(const short8*)&Bs[(wc * 64 + j * 16 + lr) * 32 + lg * 8];
#pragma unroll
    for (int i = 0; i < 4; ++i)
#pragma unroll
      for (int j = 0; j < 4; ++j)
        acc[i][j] = __builtin_amdgcn_mfma_f32_16x16x32_bf16(af[i], bfr[j], acc[i][j], 0, 0, 0);
  }

#pragma unroll
  for (int i = 0; i < 4; ++i)
#pragma unroll
    for (int j = 0; j < 4; ++j)
#pragma unroll
      for (int r2 = 0; r2 < 4; ++r2) {
        const int row = m0 + wr * 64 + i * 16 + lg * 4 + r2;
        const int col = wc * 64 + j * 16 + lr;
        float v = acc[i][j][r2];
        if (MODE == 0) {
          Cq[(size_t)row * 1024 + n0 + col] = v;
        } else {
          const int n = n0 + col;
          if (n < 1024) {
            Cq[(size_t)row * 1024 + n] = v;
          } else if (n < 2048) {
            Cv[(size_t)row * 1024 + (n - 1024)] = f2bf(v);
          } else {
            float s = v / (1.f + __expf(-v));
            Cg[(size_t)row * 1024 + (n - 2048)] = f2bf(s);
          }
        }
      }
}

// ---------------- headwise LN over 128 ----------------
template <int ADDXU>
__global__ __launch_bounds__(256) void hln_kernel(float* __restrict__ buf,
                                                  const float* __restrict__ xu) {
  int lane = threadIdx.x & 63;
  size_t row = (size_t)blockIdx.x * 4 + (threadIdx.x >> 6);
  float* p = buf + row * 128;
  float2 v = *(float2*)(p + lane * 2);
  float s = v.x + v.y;
#pragma unroll
  for (int off = 32; off; off >>= 1) s += __shfl_down(s, off);
  float mu = __shfl(s, 0) * (1.f / 128.f);
  float dx = v.x - mu, dy = v.y - mu;
  float q = dx * dx + dy * dy;
#pragma unroll
  for (int off = 32; off; off >>= 1) q += __shfl_down(q, off);
  float rs = rsqrtf(__shfl(q, 0) * (1.f / 128.f) + 1e-6f);
  float ox = dx * rs, oy = dy * rs;
  if (ADDXU) {
    int h = (int)(row & 7);
    ox += xu[h * 128 + lane * 2];
    oy += xu[h * 128 + lane * 2 + 1];
  }
  *(float2*)(p + lane * 2) = make_float2(ox, oy);
}

// ---------------- codebook transpose + norms ----------------
__global__ __launch_bounds__(128) void cbprep_kernel(const float* __restrict__ cb,
                                                     float* __restrict__ cbT,
                                                     float* __restrict__ cbn) {
  __shared__ float sm[2];
  const int hc = blockIdx.x;
  const int h = hc >> 9, c = hc & 511;
  float v = cb[(size_t)hc * 128 + threadIdx.x];
  cbT[((size_t)h * 128 + threadIdx.x) * nC + c] = v;
  float s = v * v;
#pragma unroll
  for (int off = 32; off; off >>= 1) s += __shfl_down(s, off);
  if ((threadIdx.x & 63) == 0) sm[threadIdx.x >> 6] = s;
  __syncthreads();
  if (threadIdx.x == 0) cbn[hc] = sm[0] + sm[1];
}

// ---------------- VQ argmin + loss partials (fp32, exact) ----------------
__global__ __launch_bounds__(256) void vq_kernel(const float* __restrict__ kbuf,
                                                 const float* __restrict__ cb,
                                                 const float* __restrict__ cbT,
                                                 const float* __restrict__ cbn,
                                                 const float* __restrict__ mask,
                                                 float* __restrict__ khat,
                                                 float* __restrict__ blocksq) {
  __shared__ float ksh[8][128];
  __shared__ float knorm[8];
  __shared__ float rv[256];
  __shared__ int ri[256];
  __shared__ int zsel[8];
  __shared__ float lsel[8];
  const int tid = threadIdx.x;
  const int b = blockIdx.y >> 3, h = blockIdx.y & 7;
  const int t0 = blockIdx.x * 8;
  const int r = tid >> 5, d4 = (tid & 31) * 4;
  {
    const float* kr = kbuf + ((size_t)((b * nT + t0 + r) * nH + h)) * 128 + d4;
    float4 kv = *(const float4*)kr;
    *(float4*)&ksh[r][d4] = kv;
    float sq = kv.x * kv.x + kv.y * kv.y + kv.z * kv.z + kv.w * kv.w;
#pragma unroll
    for (int off = 16; off; off >>= 1) sq += __shfl_down(sq, off, 32);
    if ((tid & 31) == 0) knorm[r] = sq;
  }
  __syncthreads();
  const int c0 = tid, c1 = tid + 256;
  float acc0[8], acc1[8];
#pragma unroll
  for (int i = 0; i < 8; ++i) { acc0[i] = 0.f; acc1[i] = 0.f; }
  const float* cbTh = cbT + (size_t)h * 128 * nC;
#pragma unroll 2
  for (int d = 0; d < 128; ++d) {
    float w0 = cbTh[(size_t)d * nC + c0];
    float w1 = cbTh[(size_t)d * nC + c1];
#pragma unroll
    for (int rr = 0; rr < 8; ++rr) {
      float kv = ksh[rr][d];
      acc0[rr] += kv * w0;
      acc1[rr] += kv * w1;
    }
  }
  const float n0v = cbn[(size_t)h * nC + c0];
  const float n1v = cbn[(size_t)h * nC + c1];
  for (int rr = 0; rr < 8; ++rr) {
    float v0 = n0v - 2.f * acc0[rr];
    float v1 = n1v - 2.f * acc1[rr];
    float bv = v0; int bi = c0;
    if (v1 < v0) { bv = v1; bi = c1; }
    rv[tid] = bv; ri[tid] = bi;
    __syncthreads();
    for (int off = 128; off; off >>= 1) {
      if (tid < off) {
        float ov = rv[tid + off]; int oi2 = ri[tid + off];
        if (ov < rv[tid] || (ov == rv[tid] && oi2 < ri[tid])) { rv[tid] = ov; ri[tid] = oi2; }
      }
      __syncthreads();
    }
    if (tid == 0) { zsel[rr] = ri[0]; lsel[rr] = knorm[rr] + rv[0]; }
    __syncthreads();
  }
  {
    float4 cv = *(const float4*)(cb + ((size_t)h * nC + zsel[r]) * 128 + d4);
    *(float4*)(khat + ((size_t)((b * nT + t0 + r) * nH + h)) * 128 + d4) = cv;
  }
  if (tid == 0) {
    float s = 0.f;
#pragma unroll
    for (int rr = 0; rr < 8; ++rr) s += mask[b * nT + t0 + rr] * lsel[rr];
    blocksq[blockIdx.y * gridDim.x + blockIdx.x] = s;
  }
}

// ---------------- MFMA flash attention ----------------
// vbuf/g are bf16 now; o written bf16 (feeds final bf16 GEMM)
__global__ __launch_bounds__(256) void attn_mfma_kernel(
    const float* __restrict__ qb, const float* __restrict__ khat,
    const ushort* __restrict__ vbuf, const float* __restrict__ xlk,
    const float* __restrict__ xlv, const float* __restrict__ cb,
    const float* __restrict__ aggU, const float* __restrict__ aggL,
    const ushort* __restrict__ gbuf, ushort* __restrict__ o) {
  __shared__ ushort Ks[64][136];
  __shared__ ushort Vts[128][72];
  __shared__ ushort Ps[4][16][72];
  __shared__ float lowb[64];

  const int tid = threadIdx.x;
  const int w = tid >> 6, l = tid & 63;
  const int lr = l & 15, lg = l >> 4;
  const int b = blockIdx.y >> 3, h = blockIdx.y & 7;
  const int t0 = blockIdx.x * 64;

  short8 qf[4];
  {
    const float* qrow = qb + ((size_t)((b * nT + t0 + w * 16 + lr) * nH + h)) * 128;
#pragma unroll
    for (int k0 = 0; k0 < 4; ++k0) {
      float4 a = *(const float4*)(qrow + k0 * 32 + lg * 8);
      float4 c = *(const float4*)(qrow + k0 * 32 + lg * 8 + 4);
      union { short8 v; uint u[4]; } t;
      t.u[0] = pk2(a.x, a.y); t.u[1] = pk2(a.z, a.w);
      t.u[2] = pk2(c.x, c.y); t.u[3] = pk2(c.z, c.w);
      qf[k0] = t.v;
    }
  }

  float m_r[4] = {-1e30f, -1e30f, -1e30f, -1e30f};
  float l_r[4] = {0.f, 0.f, 0.f, 0.f};
  f32x4 acc_o[8];
#pragma unroll
  for (int dt = 0; dt < 8; ++dt) acc_o[dt] = (f32x4){0.f, 0.f, 0.f, 0.f};

  const int srow = tid >> 2, sd = (tid & 3) * 32;
  const int kp = tid & 31, dbase = (tid >> 5) * 16;

  auto stageK = [&](const float* src) {
#pragma unroll
    for (int q4 = 0; q4 < 4; ++q4) {
      float4 a = *(const float4*)(src + q4 * 8);
      float4 c = *(const float4*)(src + q4 * 8 + 4);
      uint4 wv;
      wv.x = pk2(a.x, a.y); wv.y = pk2(a.z, a.w);
      wv.z = pk2(c.x, c.y); wv.w = pk2(c.z, c.w);
      *(uint4*)&Ks[srow][sd + q4 * 8] = wv;
    }
  };
  auto stageV = [&](const float* v0, const float* v1) {
    float4 r0[4], r1[4];
#pragma unroll
    for (int i2 = 0; i2 < 4; ++i2) {
      r0[i2] = *(const float4*)(v0 + i2 * 4);
      r1[i2] = *(const float4*)(v1 + i2 * 4);
    }
#pragma unroll
    for (int i2 = 0; i2 < 16; ++i2) {
      float a = ((const float*)r0)[i2], c = ((const float*)r1)[i2];
      *(uint*)&Vts[dbase + i2][2 * kp] = pk2(a, c);
    }
  };
  auto stageVbf = [&](const ushort* v0, const ushort* v1) {
    short8 a0 = *(const short8*)(v0);
    short8 a1 = *(const short8*)(v0 + 8);
    short8 b0 = *(const short8*)(v1);
    short8 b1 = *(const short8*)(v1 + 8);
#pragma unroll
    for (int i2 = 0; i2 < 8; ++i2) {
      *(uint*)&Vts[dbase + i2][2 * kp] = (uint)(ushort)a0[i2] | ((uint)(ushort)b0[i2] << 16);
      *(uint*)&Vts[dbase + 8 + i2][2 * kp] = (uint)(ushort)a1[i2] | ((uint)(ushort)b1[i2] << 16);
    }
  };

  auto chunk_body = [&](int sbase, bool AGG, bool MASKQ) {
    f32x4 sc[4];
#pragma unroll
    for (int kt = 0; kt < 4; ++kt) {
      f32x4 z = (f32x4){0.f, 0.f, 0.f, 0.f};
#pragma unroll
      for (int k0 = 0; k0 < 4; ++k0) {
        short8 kf = *(const short8*)&Ks[kt * 16 + lr][k0 * 32 + lg * 8];
        z = __builtin_amdgcn_mfma_f32_16x16x32_bf16(qf[k0], kf, z, 0, 0, 0);
      }
      sc[kt] = z;
    }
    float sv[4][4];
    float pm[4] = {-1e30f, -1e30f, -1e30f, -1e30f};
#pragma unroll
    for (int kt = 0; kt < 4; ++kt)
#pragma unroll
      for (int r2 = 0; r2 < 4; ++r2) {
        float s = sc[kt][r2] * RTAU;
        if (MASKQ) {
          int key = sbase + kt * 16 + lr;
          int tl = t0 + w * 16 + lg * 4 + r2 + nM;
          if (key > tl) s = -1e30f;
        }
        sv[kt][r2] = s;
        pm[r2] = fmaxf(pm[r2], s);
      }
#pragma unroll
    for (int r2 = 0; r2 < 4; ++r2)
#pragma unroll
      for (int off = 1; off < 16; off <<= 1) pm[r2] = fmaxf(pm[r2], __shfl_xor(pm[r2], off));
    float scale[4], rs[4];
#pragma unroll
    for (int r2 = 0; r2 < 4; ++r2) {
      float mn = fmaxf(m_r[r2], pm[r2]);
      scale[r2] = __expf(m_r[r2] - mn);
      m_r[r2] = mn;
      rs[r2] = 0.f;
    }
#pragma unroll
    for (int kt = 0; kt < 4; ++kt)
#pragma unroll
      for (int r2 = 0; r2 < 4; ++r2) {
        float p = __expf(sv[kt][r2] - m_r[r2]);
        rs[r2] += AGG ? p * lowb[kt * 16 + lr] : p;
        Ps[w][lg * 4 + r2][kt * 16 + lr] = f2bf(p);
      }
#pragma unroll
    for (int r2 = 0; r2 < 4; ++r2)
#pragma unroll
      for (int off = 1; off < 16; off <<= 1) rs[r2] += __shfl_xor(rs[r2], off);
#pragma unroll
    for (int r2 = 0; r2 < 4; ++r2) l_r[r2] = l_r[r2] * scale[r2] + rs[r2];
#pragma unroll
    for (int dt = 0; dt < 8; ++dt)
#pragma unroll
      for (int r2 = 0; r2 < 4; ++r2) acc_o[dt][r2] *= scale[r2];
    short8 pa0 = *(const short8*)&Ps[w][lr][lg * 8];
    short8 pa1 = *(const short8*)&Ps[w][lr][32 + lg * 8];
#pragma unroll
    for (int dt = 0; dt < 8; ++dt) {
      short8 vf0 = *(const short8*)&Vts[dt * 16 + lr][lg * 8];
      short8 vf1 = *(const short8*)&Vts[dt * 16 + lr][32 + lg * 8];
      acc_o[dt] = __builtin_amdgcn_mfma_f32_16x16x32_bf16(pa0, vf0, acc_o[dt], 0, 0, 0);
      acc_o[dt] = __builtin_amdgcn_mfma_f32_16x16x32_bf16(pa1, vf1, acc_o[dt], 0, 0, 0);
    }
  };

  const int nch = t0 / 64 + 9;
  for (int ci = 0; ci < nch; ++ci) {
    const int sbase = ci * 64;
    __syncthreads();
    {
      int s = sbase + srow;
      const float* src = (s < nM)
          ? xlk + ((size_t)(b * nH + h) * nM + s) * 128 + sd
          : khat + ((size_t)((b * nT + (s - nM)) * nH + h)) * 128 + sd;
      stageK(src);
    }
    {
      int s0 = sbase + 2 * kp;
      if (s0 < nM) {
        const float* v0 = xlv + ((size_t)(b * nH + h) * nM + s0) * 128 + dbase;
        stageV(v0, v0 + 128);
      } else {
        const ushort* v0 = vbuf + ((size_t)((b * nT + (s0 - nM)) * nH + h)) * 128 + dbase;
        stageVbf(v0, v0 + nH * 128);
      }
    }
    __syncthreads();
    chunk_body(sbase, false, ci == nch - 1);
  }

  for (int ca = 0; ca < 8; ++ca) {
    const int sbase = ca * 64;
    __syncthreads();
    stageK(cb + ((size_t)h * nC + sbase + srow) * 128 + sd);
    {
      const float* v0 = aggU + ((size_t)(b * nH + h) * nC + sbase + 2 * kp) * 128 + dbase;
      stageV(v0, v0 + 128);
    }
    if (tid < 64) lowb[tid] = aggL[(size_t)(b * nH + h) * nC + sbase + tid];
    __syncthreads();
    chunk_body(sbase, true, false);
  }

  float inv[4];
#pragma unroll
  for (int r2 = 0; r2 < 4; ++r2) inv[r2] = 1.f / l_r[r2];
#pragma unroll
  for (int dt = 0; dt < 8; ++dt)
#pragma unroll
    for (int r2 = 0; r2 < 4; ++r2) {
      int trow = t0 + w * 16 + lg * 4 + r2;
      size_t oi = ((size_t)(b * nT + trow)) * nD + h * 128 + dt * 16 + lr;
      float gv = bf2f(gbuf[oi]);
      o[oi] = f2bf(acc_o[dt][r2] * inv[r2] * gv);
    }
}

// ---------------- losses ----------------
__global__ __launch_bounds__(256) void finalize_kernel(const float* __restrict__ blocksq,
                                                       const float* __restrict__ mask,
                                                       float* __restrict__ outp) {
  __shared__ float sm[8];
  const int tid = threadIdx.x;
  float s = 0.f, ms = 0.f;
  for (int i = tid; i < NROW; i += 256) { s += blocksq[i]; ms += mask[i]; }
#pragma unroll
  for (int off = 32; off; off >>= 1) { s += __shfl_down(s, off); ms += __shfl_down(ms, off); }
  if ((tid & 63) == 0) { sm[tid >> 6] = s; sm[4 + (tid >> 6)] = ms; }
  __syncthreads();
  if (tid == 0) {
    float ts = sm[0] + sm[1] + sm[2] + sm[3];
    float tm = sm[4] + sm[5] + sm[6] + sm[7];
    float l = ts / (tm * (float)nH + 1e-6f);
    outp[0] = l;
    outp[1] = l;
  }
}

}  // namespace

extern "C" void kernel_launch(void* const* d_in, const int* in_sizes, int n_in,
                              void* d_out, int out_size, void* d_ws, size_t ws_size,
                              hipStream_t stream) {
  const float* x    = (const float*)d_in[0];
  const float* mask = (const float*)d_in[2];
  const float* xlk  = (const float*)d_in[3];
  const float* xlv  = (const float*)d_in[4];
  const float* aggU = (const float*)d_in[5];
  const float* aggL = (const float*)d_in[6];
  const float* wlng = (const float*)d_in[7];
  const float* wlnb = (const float*)d_in[8];
  const float* wq   = (const float*)d_in[9];
  const float* wk   = (const float*)d_in[10];
  const float* wv   = (const float*)d_in[11];
  const float* wg   = (const float*)d_in[12];
  const float* wres = (const float*)d_in[13];
  const float* xu   = (const float*)d_in[14];
  const float* cb   = (const float*)d_in[15];
  float* out = (float*)d_out;

  float* ws = (float*)d_ws;
  const size_t SZ = (size_t)NROW * nD;   // 4M floats
  float*  xt      = ws;                                   // fp32 (k GEMM); obuf_bf overlays later
  float*  qbuf    = ws + SZ;
  float*  kbuf    = ws + 2 * SZ;
  float*  khat    = ws + 3 * SZ;
  ushort* vbuf_bf = (ushort*)(ws + 4 * SZ);               // SZ ushorts
  ushort* gbuf_bf = (ushort*)(ws + 4 * SZ + SZ / 2);      // SZ ushorts
  ushort* xt_bf   = (ushort*)(ws + 5 * SZ);               // SZ ushorts
  ushort* wqvg_t  = (ushort*)(ws + 5 * SZ + SZ / 2);      // 3072*1024 ushorts
  ushort* wres_t  = wqvg_t + (size_t)3072 * 1024;         // 1024*1024 ushorts
  float*  cbT     = (float*)(wres_t + (size_t)1024 * 1024);
  float*  cbn     = cbT + (size_t)nH * nC * 128;
  float*  bsq     = cbn + (size_t)nH * nC;
  ushort* obuf_bf = (ushort*)xt;   // xt fp32 dead after k GEMM

  ln_kernel<<<NROW, 256, 0, stream>>>(x, wlng, wlnb, xt, xt_bf);
  wtrans_kernel<<<dim3(16, 16, 4), 256, 0, stream>>>(wq, wv, wg, wres, wqvg_t, wres_t);
  cbprep_kernel<<<nH * nC, 128, 0, stream>>>(cb, cbT, cbn);

  // k projection in fp32 (exact VQ argmin path)
  gemm_kernel<0><<<dim3(nD / 64, NROW / 128), 256, 0, stream>>>(xt, wk, kbuf);
  // fused q|v|g projection in bf16 MFMA
  gemm_bf16_kernel<1><<<dim3(24, 32), 256, 0, stream>>>(xt_bf, wqvg_t, qbuf, vbuf_bf, gbuf_bf);

  hln_kernel<1><<<(NROW * nH) / 4, 256, 0, stream>>>(qbuf, xu);
  hln_kernel<0><<<(NROW * nH) / 4, 256, 0, stream>>>(kbuf, nullptr);

  vq_kernel<<<dim3(nT / 8, nB * nH), 256, 0, stream>>>(kbuf, cb, cbT, cbn, mask, khat, bsq);

  attn_mfma_kernel<<<dim3(nT / 64, nB * nH), 256, 0, stream>>>(
      qbuf, khat, vbuf_bf, xlk, xlv, cb, aggU, aggL, gbuf_bf, obuf_bf);

  // final projection in bf16 MFMA
  gemm_bf16_kernel<0><<<dim3(8, 32), 256, 0, stream>>>(obuf_bf, wres_t, out, nullptr, nullptr);
  finalize_kernel<<<1, 256, 0, stream>>>(bsq, mask, out + SZ);
}

// Round 7
// 333.476 us; speedup vs baseline: 4.7373x; 1.3755x over previous
//
#include <hip/hip_runtime.h>
#include <math.h>

namespace {

constexpr int nB = 8, nT = 512, nD = 1024, nH = 8, nDK = 128, nDV = 128, nC = 512, nM = 512;
constexpr int NROW = nB * nT;                  // 4096
constexpr float RTAU = 0.08838834764831845f;   // 1/sqrt(128)

typedef __attribute__((ext_vector_type(8))) short short8;
typedef __attribute__((ext_vector_type(4))) float f32x4;

__device__ __forceinline__ ushort f2bf(float f) {
  union { float f; uint u; } x; x.f = f;
  uint r = x.u + 0x7fff + ((x.u >> 16) & 1);
  return (ushort)(r >> 16);
}
__device__ __forceinline__ uint pk2(float a, float b) {
  return (uint)f2bf(a) | ((uint)f2bf(b) << 16);
}
__device__ __forceinline__ float bf2f(ushort u) {
  return __uint_as_float(((uint)u) << 16);
}
__device__ __forceinline__ void gload16(const void* g, void* l) {
  __builtin_amdgcn_global_load_lds((const __attribute__((address_space(1))) void*)g,
                                   (__attribute__((address_space(3))) void*)l, 16, 0, 0);
}

__device__ __forceinline__ float blockReduce256(float v, float* sm) {
  int lane = threadIdx.x & 63, w = threadIdx.x >> 6;
#pragma unroll
  for (int off = 32; off; off >>= 1) v += __shfl_down(v, off);
  if (lane == 0) sm[w] = v;
  __syncthreads();
  float r = sm[0] + sm[1] + sm[2] + sm[3];
  __syncthreads();
  return r;
}

// ---------------- LayerNorm -> bf16 xt ----------------
__global__ __launch_bounds__(256) void ln_kernel(const float* __restrict__ x,
                                                 const float* __restrict__ gw,
                                                 const float* __restrict__ bw,
                                                 ushort* __restrict__ xt_bf) {
  __shared__ float sm[4];
  size_t row = blockIdx.x;
  float4 v = ((const float4*)(x + row * nD))[threadIdx.x];
  float mu = blockReduce256(v.x + v.y + v.z + v.w, sm) * (1.f / nD);
  float4 d = make_float4(v.x - mu, v.y - mu, v.z - mu, v.w - mu);
  float var = blockReduce256(d.x * d.x + d.y * d.y + d.z * d.z + d.w * d.w, sm) * (1.f / nD);
  float rs = rsqrtf(var + 1e-6f);
  float4 gg = ((const float4*)gw)[threadIdx.x];
  float4 bb = ((const float4*)bw)[threadIdx.x];
  float4 o = make_float4(d.x * rs * gg.x + bb.x, d.y * rs * gg.y + bb.y,
                         d.z * rs * gg.z + bb.z, d.w * rs * gg.w + bb.w);
  uint2 pb;
  pb.x = pk2(o.x, o.y);
  pb.y = pk2(o.z, o.w);
  ((uint2*)(xt_bf + row * nD))[threadIdx.x] = pb;
}

// ---------------- fp32 -> bf16 cast (grid-stride over float4) ----------------
__global__ __launch_bounds__(256) void tobf_kernel(const float* __restrict__ src,
                                                   ushort* __restrict__ dst) {
  size_t i = (size_t)blockIdx.x * 256 + threadIdx.x;
  float4 v = ((const float4*)src)[i];
  uint2 p;
  p.x = pk2(v.x, v.y);
  p.y = pk2(v.z, v.w);
  ((uint2*)dst)[i] = p;
}

// ---------------- weight transpose + bf16: D[n][k] = bf16(W[k][n]) ----------------
__global__ __launch_bounds__(256) void wtrans_kernel(const float* __restrict__ wq,
                                                     const float* __restrict__ wk,
                                                     const float* __restrict__ wv,
                                                     const float* __restrict__ wg,
                                                     const float* __restrict__ wres,
                                                     ushort* __restrict__ wqkvg_t,
                                                     ushort* __restrict__ wres_t) {
  __shared__ float tile[64][65];
  const int kz = blockIdx.x * 64;
  const int nz = blockIdx.y * 64;
  const float* W;
  ushort* D;
  if (blockIdx.z == 0)      { W = wq;   D = wqkvg_t; }
  else if (blockIdx.z == 1) { W = wk;   D = wqkvg_t + (size_t)1024 * 1024; }
  else if (blockIdx.z == 2) { W = wv;   D = wqkvg_t + (size_t)2048 * 1024; }
  else if (blockIdx.z == 3) { W = wg;   D = wqkvg_t + (size_t)3072 * 1024; }
  else                      { W = wres; D = wres_t; }
  const int c = threadIdx.x & 63, r4 = threadIdx.x >> 6;
#pragma unroll
  for (int i = 0; i < 16; ++i) {
    int r = i * 4 + r4;
    tile[r][c] = W[(size_t)(kz + r) * 1024 + nz + c];
  }
  __syncthreads();
#pragma unroll
  for (int i = 0; i < 16; ++i) {
    int n = i * 4 + r4;
    D[(size_t)(nz + n) * 1024 + kz + c] = f2bf(tile[c][n]);
  }
}

// ---------------- bf16 MFMA GEMM (128x128 tile, BK=32) ----------------
// A: [M][1024] bf16 row-major.  Bt: [N][1024] bf16 row-major.
// MODE 0: out fp32 -> C0[row*1024 + n0+col]
// MODE 1 (fused q|k|v|g, N=4096): seg0 q->C1 bf16; seg1 k->C0 fp32; seg2 v->C2 bf16; seg3 silu->C3 bf16
template <int MODE>
__global__ __launch_bounds__(256) void gemm_bf16_kernel(const ushort* __restrict__ A,
                                                        const ushort* __restrict__ Bt,
                                                        float* __restrict__ C0,
                                                        ushort* __restrict__ C1,
                                                        ushort* __restrict__ C2,
                                                        ushort* __restrict__ C3) {
  __shared__ __align__(16) ushort As[128 * 32];
  __shared__ __align__(16) ushort Bs[128 * 32];
  const int tid = threadIdx.x;
  const int w = tid >> 6, l = tid & 63;
  const int lr = l & 15, lg = l >> 4;
  const int wr = w >> 1, wc = w & 1;
  const int n0 = blockIdx.x * 128;
  const int m0 = blockIdx.y * 128;
  constexpr int K = 1024;

  f32x4 acc[4][4];
#pragma unroll
  for (int i = 0; i < 4; ++i)
#pragma unroll
    for (int j = 0; j < 4; ++j) acc[i][j] = (f32x4){0.f, 0.f, 0.f, 0.f};

  const int e0 = w * 512 + l * 8;
  const int r0 = e0 >> 5, c0 = e0 & 31;
  const int e1 = 2048 + e0;
  const int r1 = e1 >> 5, c1 = e1 & 31;
  const ushort* a0p = A + (size_t)(m0 + r0) * K + c0;
  const ushort* a1p = A + (size_t)(m0 + r1) * K + c1;
  const ushort* b0p = Bt + (size_t)(n0 + r0) * K + c0;
  const ushort* b1p = Bt + (size_t)(n0 + r1) * K + c1;
  ushort* lA0 = &As[w * 512];
  ushort* lA1 = &As[2048 + w * 512];
  ushort* lB0 = &Bs[w * 512];
  ushort* lB1 = &Bs[2048 + w * 512];

  for (int k0 = 0; k0 < K; k0 += 32) {
    __syncthreads();
    gload16(a0p + k0, lA0);
    gload16(a1p + k0, lA1);
    gload16(b0p + k0, lB0);
    gload16(b1p + k0, lB1);
    __syncthreads();
    short8 af[4], bfr[4];
#pragma unroll
    for (int i = 0; i < 4; ++i) af[i] = *(const short8*)&As[(wr * 64 + i * 16 + lr) * 32 + lg * 8];
#pragma unroll
    for (int j = 0; j < 4; ++j) bfr[j] = *(const short8*)&Bs[(wc * 64 + j * 16 + lr) * 32 + lg * 8];
#pragma unroll
    for (int i = 0; i < 4; ++i)
#pragma unroll
      for (int j = 0; j < 4; ++j)
        acc[i][j] = __builtin_amdgcn_mfma_f32_16x16x32_bf16(af[i], bfr[j], acc[i][j], 0, 0, 0);
  }

  const int seg = n0 >> 10;
  const int nbase = n0 & 1023;
#pragma unroll
  for (int i = 0; i < 4; ++i)
#pragma unroll
    for (int j = 0; j < 4; ++j)
#pragma unroll
      for (int r2 = 0; r2 < 4; ++r2) {
        const int row = m0 + wr * 64 + i * 16 + lg * 4 + r2;
        const int col = wc * 64 + j * 16 + lr;
        float v = acc[i][j][r2];
        if (MODE == 0) {
          C0[(size_t)row * 1024 + n0 + col] = v;
        } else {
          const int nloc = nbase + col;
          if (seg == 0)      C1[(size_t)row * 1024 + nloc] = f2bf(v);
          else if (seg == 1) C0[(size_t)row * 1024 + nloc] = v;
          else if (seg == 2) C2[(size_t)row * 1024 + nloc] = f2bf(v);
          else {
            float s = v / (1.f + __expf(-v));
            C3[(size_t)row * 1024 + nloc] = f2bf(s);
          }
        }
      }
}

// ---------------- headwise LN over 128, fp32 in-place (k path) ----------------
__global__ __launch_bounds__(256) void hln_kernel(float* __restrict__ buf) {
  int lane = threadIdx.x & 63;
  size_t row = (size_t)blockIdx.x * 4 + (threadIdx.x >> 6);
  float* p = buf + row * 128;
  float2 v = *(float2*)(p + lane * 2);
  float s = v.x + v.y;
#pragma unroll
  for (int off = 32; off; off >>= 1) s += __shfl_down(s, off);
  float mu = __shfl(s, 0) * (1.f / 128.f);
  float dx = v.x - mu, dy = v.y - mu;
  float q = dx * dx + dy * dy;
#pragma unroll
  for (int off = 32; off; off >>= 1) q += __shfl_down(q, off);
  float rs = rsqrtf(__shfl(q, 0) * (1.f / 128.f) + 1e-6f);
  *(float2*)(p + lane * 2) = make_float2(dx * rs, dy * rs);
}

// ---------------- headwise LN over 128, bf16 in-place + xu (q path) ----------------
__global__ __launch_bounds__(256) void hln_bf_kernel(ushort* __restrict__ buf,
                                                     const float* __restrict__ xu) {
  int lane = threadIdx.x & 63;
  size_t row = (size_t)blockIdx.x * 4 + (threadIdx.x >> 6);
  ushort* p = buf + row * 128;
  uint u = *(uint*)(p + lane * 2);
  float vx = bf2f((ushort)(u & 0xffff)), vy = bf2f((ushort)(u >> 16));
  float s = vx + vy;
#pragma unroll
  for (int off = 32; off; off >>= 1) s += __shfl_down(s, off);
  float mu = __shfl(s, 0) * (1.f / 128.f);
  float dx = vx - mu, dy = vy - mu;
  float q = dx * dx + dy * dy;
#pragma unroll
  for (int off = 32; off; off >>= 1) q += __shfl_down(q, off);
  float rs = rsqrtf(__shfl(q, 0) * (1.f / 128.f) + 1e-6f);
  int h = (int)(row & 7);
  float ox = dx * rs + xu[h * 128 + lane * 2];
  float oy = dy * rs + xu[h * 128 + lane * 2 + 1];
  *(uint*)(p + lane * 2) = pk2(ox, oy);
}

// ---------------- codebook transpose + norms + bf16 copy ----------------
__global__ __launch_bounds__(128) void cbprep_kernel(const float* __restrict__ cb,
                                                     float* __restrict__ cbT,
                                                     float* __restrict__ cbn,
                                                     ushort* __restrict__ cb_bf) {
  __shared__ float sm[2];
  const int hc = blockIdx.x;
  const int h = hc >> 9, c = hc & 511;
  float v = cb[(size_t)hc * 128 + threadIdx.x];
  cbT[((size_t)h * 128 + threadIdx.x) * nC + c] = v;
  cb_bf[(size_t)hc * 128 + threadIdx.x] = f2bf(v);
  float s = v * v;
#pragma unroll
  for (int off = 32; off; off >>= 1) s += __shfl_down(s, off);
  if ((threadIdx.x & 63) == 0) sm[threadIdx.x >> 6] = s;
  __syncthreads();
  if (threadIdx.x == 0) cbn[hc] = sm[0] + sm[1];
}

// ---------------- VQ argmin + loss partials; khat written bf16 ----------------
__global__ __launch_bounds__(256) void vq_kernel(const float* __restrict__ kbuf,
                                                 const ushort* __restrict__ cb_bf,
                                                 const float* __restrict__ cbT,
                                                 const float* __restrict__ cbn,
                                                 const float* __restrict__ mask,
                                                 ushort* __restrict__ khat_bf,
                                                 float* __restrict__ blocksq) {
  __shared__ float ksh[8][128];
  __shared__ float knorm[8];
  __shared__ float rv[256];
  __shared__ int ri[256];
  __shared__ int zsel[8];
  __shared__ float lsel[8];
  const int tid = threadIdx.x;
  const int b = blockIdx.y >> 3, h = blockIdx.y & 7;
  const int t0 = blockIdx.x * 8;
  const int r = tid >> 5, d4 = (tid & 31) * 4;
  {
    const float* kr = kbuf + ((size_t)((b * nT + t0 + r) * nH + h)) * 128 + d4;
    float4 kv = *(const float4*)kr;
    *(float4*)&ksh[r][d4] = kv;
    float sq = kv.x * kv.x + kv.y * kv.y + kv.z * kv.z + kv.w * kv.w;
#pragma unroll
    for (int off = 16; off; off >>= 1) sq += __shfl_down(sq, off, 32);
    if ((tid & 31) == 0) knorm[r] = sq;
  }
  __syncthreads();
  const int c0 = tid, c1 = tid + 256;
  float acc0[8], acc1[8];
#pragma unroll
  for (int i = 0; i < 8; ++i) { acc0[i] = 0.f; acc1[i] = 0.f; }
  const float* cbTh = cbT + (size_t)h * 128 * nC;
#pragma unroll 2
  for (int d = 0; d < 128; ++d) {
    float w0 = cbTh[(size_t)d * nC + c0];
    float w1 = cbTh[(size_t)d * nC + c1];
#pragma unroll
    for (int rr = 0; rr < 8; ++rr) {
      float kv = ksh[rr][d];
      acc0[rr] += kv * w0;
      acc1[rr] += kv * w1;
    }
  }
  const float n0v = cbn[(size_t)h * nC + c0];
  const float n1v = cbn[(size_t)h * nC + c1];
  for (int rr = 0; rr < 8; ++rr) {
    float v0 = n0v - 2.f * acc0[rr];
    float v1 = n1v - 2.f * acc1[rr];
    float bv = v0; int bi = c0;
    if (v1 < v0) { bv = v1; bi = c1; }
    rv[tid] = bv; ri[tid] = bi;
    __syncthreads();
    for (int off = 128; off; off >>= 1) {
      if (tid < off) {
        float ov = rv[tid + off]; int oi2 = ri[tid + off];
        if (ov < rv[tid] || (ov == rv[tid] && oi2 < ri[tid])) { rv[tid] = ov; ri[tid] = oi2; }
      }
      __syncthreads();
    }
    if (tid == 0) { zsel[rr] = ri[0]; lsel[rr] = knorm[rr] + rv[0]; }
    __syncthreads();
  }
  {
    uint2 cv = *(const uint2*)(cb_bf + ((size_t)h * nC + zsel[r]) * 128 + d4);
    *(uint2*)(khat_bf + ((size_t)((b * nT + t0 + r) * nH + h)) * 128 + d4) = cv;
  }
  if (tid == 0) {
    float s = 0.f;
#pragma unroll
    for (int rr = 0; rr < 8; ++rr) s += mask[b * nT + t0 + rr] * lsel[rr];
    blocksq[blockIdx.y * gridDim.x + blockIdx.x] = s;
  }
}

// ---------------- MFMA flash attention (all K/V/Q operands bf16) ----------------
__global__ __launch_bounds__(256) void attn_mfma_kernel(
    const ushort* __restrict__ qb, const ushort* __restrict__ khat,
    const ushort* __restrict__ vbuf, const ushort* __restrict__ xlk,
    const ushort* __restrict__ xlv, const ushort* __restrict__ cbb,
    const ushort* __restrict__ aggU, const float* __restrict__ aggL,
    const ushort* __restrict__ gbuf, ushort* __restrict__ o) {
  __shared__ ushort Ks[64][136];
  __shared__ ushort Vts[128][72];
  __shared__ ushort Ps[4][16][72];
  __shared__ float lowb[64];

  const int tid = threadIdx.x;
  const int w = tid >> 6, l = tid & 63;
  const int lr = l & 15, lg = l >> 4;
  const int b = blockIdx.y >> 3, h = blockIdx.y & 7;
  const int t0 = blockIdx.x * 64;

  short8 qf[4];
  {
    const ushort* qrow = qb + ((size_t)((b * nT + t0 + w * 16 + lr) * nH + h)) * 128;
#pragma unroll
    for (int k0 = 0; k0 < 4; ++k0) qf[k0] = *(const short8*)(qrow + k0 * 32 + lg * 8);
  }

  float m_r[4] = {-1e30f, -1e30f, -1e30f, -1e30f};
  float l_r[4] = {0.f, 0.f, 0.f, 0.f};
  f32x4 acc_o[8];
#pragma unroll
  for (int dt = 0; dt < 8; ++dt) acc_o[dt] = (f32x4){0.f, 0.f, 0.f, 0.f};

  const int srow = tid >> 2, sd = (tid & 3) * 32;
  const int kp = tid & 31, dbase = (tid >> 5) * 16;

  // pure copy: 64B contiguous from bf16 row into Ks
  auto stageK = [&](const ushort* src) {
#pragma unroll
    for (int q4 = 0; q4 < 4; ++q4)
      *(uint4*)&Ks[srow][sd + q4 * 8] = *(const uint4*)(src + q4 * 8);
  };
  // transpose-pack two bf16 V rows into Vts
  auto stageVbf = [&](const ushort* v0, const ushort* v1) {
    short8 a0 = *(const short8*)(v0);
    short8 a1 = *(const short8*)(v0 + 8);
    short8 b0 = *(const short8*)(v1);
    short8 b1 = *(const short8*)(v1 + 8);
#pragma unroll
    for (int i2 = 0; i2 < 8; ++i2) {
      *(uint*)&Vts[dbase + i2][2 * kp] = (uint)(ushort)a0[i2] | ((uint)(ushort)b0[i2] << 16);
      *(uint*)&Vts[dbase + 8 + i2][2 * kp] = (uint)(ushort)a1[i2] | ((uint)(ushort)b1[i2] << 16);
    }
  };

  auto chunk_body = [&](int sbase, bool AGG, bool MASKQ) {
    f32x4 sc[4];
#pragma unroll
    for (int kt = 0; kt < 4; ++kt) {
      f32x4 z = (f32x4){0.f, 0.f, 0.f, 0.f};
#pragma unroll
      for (int k0 = 0; k0 < 4; ++k0) {
        short8 kf = *(const short8*)&Ks[kt * 16 + lr][k0 * 32 + lg * 8];
        z = __builtin_amdgcn_mfma_f32_16x16x32_bf16(qf[k0], kf, z, 0, 0, 0);
      }
      sc[kt] = z;
    }
    float sv[4][4];
    float pm[4] = {-1e30f, -1e30f, -1e30f, -1e30f};
#pragma unroll
    for (int kt = 0; kt < 4; ++kt)
#pragma unroll
      for (int r2 = 0; r2 < 4; ++r2) {
        float s = sc[kt][r2] * RTAU;
        if (MASKQ) {
          int key = sbase + kt * 16 + lr;
          int tl = t0 + w * 16 + lg * 4 + r2 + nM;
          if (key > tl) s = -1e30f;
        }
        sv[kt][r2] = s;
        pm[r2] = fmaxf(pm[r2], s);
      }
#pragma unroll
    for (int r2 = 0; r2 < 4; ++r2)
#pragma unroll
      for (int off = 1; off < 16; off <<= 1) pm[r2] = fmaxf(pm[r2], __shfl_xor(pm[r2], off));
    float scale[4], rs[4];
#pragma unroll
    for (int r2 = 0; r2 < 4; ++r2) {
      float mn = fmaxf(m_r[r2], pm[r2]);
      scale[r2] = __expf(m_r[r2] - mn);
      m_r[r2] = mn;
      rs[r2] = 0.f;
    }
#pragma unroll
    for (int kt = 0; kt < 4; ++kt)
#pragma unroll
      for (int r2 = 0; r2 < 4; ++r2) {
        float p = __expf(sv[kt][r2] - m_r[r2]);
        rs[r2] += AGG ? p * lowb[kt * 16 + lr] : p;
        Ps[w][lg * 4 + r2][kt * 16 + lr] = f2bf(p);
      }
#pragma unroll
    for (int r2 = 0; r2 < 4; ++r2)
#pragma unroll
      for (int off = 1; off < 16; off <<= 1) rs[r2] += __shfl_xor(rs[r2], off);
#pragma unroll
    for (int r2 = 0; r2 < 4; ++r2) l_r[r2] = l_r[r2] * scale[r2] + rs[r2];
#pragma unroll
    for (int dt = 0; dt < 8; ++dt)
#pragma unroll
      for (int r2 = 0; r2 < 4; ++r2) acc_o[dt][r2] *= scale[r2];
    short8 pa0 = *(const short8*)&Ps[w][lr][lg * 8];
    short8 pa1 = *(const short8*)&Ps[w][lr][32 + lg * 8];
#pragma unroll
    for (int dt = 0; dt < 8; ++dt) {
      short8 vf0 = *(const short8*)&Vts[dt * 16 + lr][lg * 8];
      short8 vf1 = *(const short8*)&Vts[dt * 16 + lr][32 + lg * 8];
      acc_o[dt] = __builtin_amdgcn_mfma_f32_16x16x32_bf16(pa0, vf0, acc_o[dt], 0, 0, 0);
      acc_o[dt] = __builtin_amdgcn_mfma_f32_16x16x32_bf16(pa1, vf1, acc_o[dt], 0, 0, 0);
    }
  };

  const int nch = t0 / 64 + 9;
  for (int ci = 0; ci < nch; ++ci) {
    const int sbase = ci * 64;
    __syncthreads();
    {
      int s = sbase + srow;
      const ushort* src = (s < nM)
          ? xlk + ((size_t)(b * nH + h) * nM + s) * 128 + sd
          : khat + ((size_t)((b * nT + (s - nM)) * nH + h)) * 128 + sd;
      stageK(src);
    }
    {
      int s0 = sbase + 2 * kp;
      if (s0 < nM) {
        const ushort* v0 = xlv + ((size_t)(b * nH + h) * nM + s0) * 128 + dbase;
        stageVbf(v0, v0 + 128);
      } else {
        const ushort* v0 = vbuf + ((size_t)((b * nT + (s0 - nM)) * nH + h)) * 128 + dbase;
        stageVbf(v0, v0 + nH * 128);
      }
    }
    __syncthreads();
    chunk_body(sbase, false, ci == nch - 1);
  }

  for (int ca = 0; ca < 8; ++ca) {
    const int sbase = ca * 64;
    __syncthreads();
    stageK(cbb + ((size_t)h * nC + sbase + srow) * 128 + sd);
    {
      const ushort* v0 = aggU + ((size_t)(b * nH + h) * nC + sbase + 2 * kp) * 128 + dbase;
      stageVbf(v0, v0 + 128);
    }
    if (tid < 64) lowb[tid] = aggL[(size_t)(b * nH + h) * nC + sbase + tid];
    __syncthreads();
    chunk_body(sbase, true, false);
  }

  float inv[4];
#pragma unroll
  for (int r2 = 0; r2 < 4; ++r2) inv[r2] = 1.f / l_r[r2];
#pragma unroll
  for (int dt = 0; dt < 8; ++dt)
#pragma unroll
    for (int r2 = 0; r2 < 4; ++r2) {
      int trow = t0 + w * 16 + lg * 4 + r2;
      size_t oi = ((size_t)(b * nT + trow)) * nD + h * 128 + dt * 16 + lr;
      float gv = bf2f(gbuf[oi]);
      o[oi] = f2bf(acc_o[dt][r2] * inv[r2] * gv);
    }
}

// ---------------- losses ----------------
__global__ __launch_bounds__(256) void finalize_kernel(const float* __restrict__ blocksq,
                                                       const float* __restrict__ mask,
                                                       float* __restrict__ outp) {
  __shared__ float sm[8];
  const int tid = threadIdx.x;
  float s = 0.f, ms = 0.f;
  for (int i = tid; i < NROW; i += 256) { s += blocksq[i]; ms += mask[i]; }
#pragma unroll
  for (int off = 32; off; off >>= 1) { s += __shfl_down(s, off); ms += __shfl_down(ms, off); }
  if ((tid & 63) == 0) { sm[tid >> 6] = s; sm[4 + (tid >> 6)] = ms; }
  __syncthreads();
  if (tid == 0) {
    float ts = sm[0] + sm[1] + sm[2] + sm[3];
    float tm = sm[4] + sm[5] + sm[6] + sm[7];
    float l = ts / (tm * (float)nH + 1e-6f);
    outp[0] = l;
    outp[1] = l;
  }
}

}  // namespace

extern "C" void kernel_launch(void* const* d_in, const int* in_sizes, int n_in,
                              void* d_out, int out_size, void* d_ws, size_t ws_size,
                              hipStream_t stream) {
  const float* x    = (const float*)d_in[0];
  const float* mask = (const float*)d_in[2];
  const float* xlk  = (const float*)d_in[3];
  const float* xlv  = (const float*)d_in[4];
  const float* aggU = (const float*)d_in[5];
  const float* aggL = (const float*)d_in[6];
  const float* wlng = (const float*)d_in[7];
  const float* wlnb = (const float*)d_in[8];
  const float* wq   = (const float*)d_in[9];
  const float* wk   = (const float*)d_in[10];
  const float* wv   = (const float*)d_in[11];
  const float* wg   = (const float*)d_in[12];
  const float* wres = (const float*)d_in[13];
  const float* xu   = (const float*)d_in[14];
  const float* cb   = (const float*)d_in[15];
  float* out = (float*)d_out;

  float* ws = (float*)d_ws;
  const size_t SZ = (size_t)NROW * nD;   // 4,194,304
  float*  kbuf    = ws;                                    // SZ floats
  ushort* qbuf_bf = (ushort*)(ws + SZ);                    // SZ ushorts
  ushort* khat_bf = (ushort*)(ws + SZ + SZ / 2);           // SZ ushorts
  ushort* vbuf_bf = (ushort*)(ws + 2 * SZ);                // SZ ushorts
  ushort* gbuf_bf = (ushort*)(ws + 2 * SZ + SZ / 2);       // SZ ushorts
  ushort* xt_bf   = (ushort*)(ws + 3 * SZ);                // SZ ushorts (obuf overlays)
  ushort* wqkvg_t = (ushort*)(ws + 3 * SZ + SZ / 2);       // 4096*1024 = SZ ushorts
  ushort* wres_t  = (ushort*)(ws + 4 * SZ);                // 1024*1024 ushorts
  ushort* xlk_bf  = (ushort*)(ws + 4 * SZ + SZ / 8);       // SZ ushorts
  ushort* xlv_bf  = (ushort*)(ws + 4 * SZ + SZ / 8 + SZ / 2);
  ushort* aggU_bf = (ushort*)(ws + 4 * SZ + SZ / 8 + SZ);
  ushort* cb_bf   = (ushort*)(ws + 4 * SZ + SZ / 8 + 3 * SZ / 2);  // 524288 ushorts
  float*  cbT     = ws + 4 * SZ + SZ / 8 + 3 * SZ / 2 + SZ / 16;   // 524288 floats
  float*  cbn     = cbT + (size_t)524288;                  // 4096 floats
  float*  bsq     = cbn + (size_t)nH * nC;                 // 4096 floats
  ushort* obuf_bf = xt_bf;   // xt_bf dead after fused GEMM

  ln_kernel<<<NROW, 256, 0, stream>>>(x, wlng, wlnb, xt_bf);
  wtrans_kernel<<<dim3(16, 16, 5), 256, 0, stream>>>(wq, wk, wv, wg, wres, wqkvg_t, wres_t);
  cbprep_kernel<<<nH * nC, 128, 0, stream>>>(cb, cbT, cbn, cb_bf);
  tobf_kernel<<<4096, 256, 0, stream>>>(xlk, xlk_bf);
  tobf_kernel<<<4096, 256, 0, stream>>>(xlv, xlv_bf);
  tobf_kernel<<<4096, 256, 0, stream>>>(aggU, aggU_bf);

  // fused q|k|v|g projection in bf16 MFMA (k written fp32 for VQ path)
  gemm_bf16_kernel<1><<<dim3(32, 32), 256, 0, stream>>>(xt_bf, wqkvg_t, kbuf,
                                                        qbuf_bf, vbuf_bf, gbuf_bf);

  hln_bf_kernel<<<(NROW * nH) / 4, 256, 0, stream>>>(qbuf_bf, xu);
  hln_kernel<<<(NROW * nH) / 4, 256, 0, stream>>>(kbuf);

  vq_kernel<<<dim3(nT / 8, nB * nH), 256, 0, stream>>>(kbuf, cb_bf, cbT, cbn, mask,
                                                       khat_bf, bsq);

  attn_mfma_kernel<<<dim3(nT / 64, nB * nH), 256, 0, stream>>>(
      qbuf_bf, khat_bf, vbuf_bf, xlk_bf, xlv_bf, cb_bf, aggU_bf, aggL, gbuf_bf, obuf_bf);

  gemm_bf16_kernel<0><<<dim3(8, 32), 256, 0, stream>>>(obuf_bf, wres_t, out,
                                                       nullptr, nullptr, nullptr);
  finalize_kernel<<<1, 256, 0, stream>>>(bsq, mask, out + SZ);
}

// Round 8
// 261.107 us; speedup vs baseline: 6.0503x; 1.2772x over previous
//
#include <hip/hip_runtime.h>
#include <math.h>

namespace {

constexpr int nB = 8, nT = 512, nD = 1024, nH = 8, nDK = 128, nDV = 128, nC = 512, nM = 512;
constexpr int NROW = nB * nT;                  // 4096
constexpr float RTAU = 0.08838834764831845f;   // 1/sqrt(128)

typedef __attribute__((ext_vector_type(8))) short short8;
typedef __attribute__((ext_vector_type(4))) float f32x4;

__device__ __forceinline__ ushort f2bf(float f) {
  union { float f; uint u; } x; x.f = f;
  uint r = x.u + 0x7fff + ((x.u >> 16) & 1);
  return (ushort)(r >> 16);
}
__device__ __forceinline__ uint pk2(float a, float b) {
  return (uint)f2bf(a) | ((uint)f2bf(b) << 16);
}
__device__ __forceinline__ float bf2f(ushort u) {
  return __uint_as_float(((uint)u) << 16);
}
__device__ __forceinline__ void gload16(const void* g, void* l) {
  __builtin_amdgcn_global_load_lds((const __attribute__((address_space(1))) void*)g,
                                   (__attribute__((address_space(3))) void*)l, 16, 0, 0);
}

__device__ __forceinline__ float blockReduce256(float v, float* sm) {
  int lane = threadIdx.x & 63, w = threadIdx.x >> 6;
#pragma unroll
  for (int off = 32; off; off >>= 1) v += __shfl_down(v, off);
  if (lane == 0) sm[w] = v;
  __syncthreads();
  float r = sm[0] + sm[1] + sm[2] + sm[3];
  __syncthreads();
  return r;
}

// ---------------- LayerNorm -> bf16 xt ----------------
__global__ __launch_bounds__(256) void ln_kernel(const float* __restrict__ x,
                                                 const float* __restrict__ gw,
                                                 const float* __restrict__ bw,
                                                 ushort* __restrict__ xt_bf) {
  __shared__ float sm[4];
  size_t row = blockIdx.x;
  float4 v = ((const float4*)(x + row * nD))[threadIdx.x];
  float mu = blockReduce256(v.x + v.y + v.z + v.w, sm) * (1.f / nD);
  float4 d = make_float4(v.x - mu, v.y - mu, v.z - mu, v.w - mu);
  float var = blockReduce256(d.x * d.x + d.y * d.y + d.z * d.z + d.w * d.w, sm) * (1.f / nD);
  float rs = rsqrtf(var + 1e-6f);
  float4 gg = ((const float4*)gw)[threadIdx.x];
  float4 bb = ((const float4*)bw)[threadIdx.x];
  float4 o = make_float4(d.x * rs * gg.x + bb.x, d.y * rs * gg.y + bb.y,
                         d.z * rs * gg.z + bb.z, d.w * rs * gg.w + bb.w);
  uint2 pb;
  pb.x = pk2(o.x, o.y);
  pb.y = pk2(o.z, o.w);
  ((uint2*)(xt_bf + row * nD))[threadIdx.x] = pb;
}

// ---------------- fp32 -> bf16 cast (grid-stride over float4) ----------------
__global__ __launch_bounds__(256) void tobf_kernel(const float* __restrict__ src,
                                                   ushort* __restrict__ dst) {
  size_t i = (size_t)blockIdx.x * 256 + threadIdx.x;
  float4 v = ((const float4*)src)[i];
  uint2 p;
  p.x = pk2(v.x, v.y);
  p.y = pk2(v.z, v.w);
  ((uint2*)dst)[i] = p;
}

// ---------------- weight transpose + bf16: D[n][k] = bf16(W[k][n]) ----------------
__global__ __launch_bounds__(256) void wtrans_kernel(const float* __restrict__ wq,
                                                     const float* __restrict__ wk,
                                                     const float* __restrict__ wv,
                                                     const float* __restrict__ wg,
                                                     const float* __restrict__ wres,
                                                     ushort* __restrict__ wqkvg_t,
                                                     ushort* __restrict__ wres_t) {
  __shared__ float tile[64][65];
  const int kz = blockIdx.x * 64;
  const int nz = blockIdx.y * 64;
  const float* W;
  ushort* D;
  if (blockIdx.z == 0)      { W = wq;   D = wqkvg_t; }
  else if (blockIdx.z == 1) { W = wk;   D = wqkvg_t + (size_t)1024 * 1024; }
  else if (blockIdx.z == 2) { W = wv;   D = wqkvg_t + (size_t)2048 * 1024; }
  else if (blockIdx.z == 3) { W = wg;   D = wqkvg_t + (size_t)3072 * 1024; }
  else                      { W = wres; D = wres_t; }
  const int c = threadIdx.x & 63, r4 = threadIdx.x >> 6;
#pragma unroll
  for (int i = 0; i < 16; ++i) {
    int r = i * 4 + r4;
    tile[r][c] = W[(size_t)(kz + r) * 1024 + nz + c];
  }
  __syncthreads();
#pragma unroll
  for (int i = 0; i < 16; ++i) {
    int n = i * 4 + r4;
    D[(size_t)(nz + n) * 1024 + kz + c] = f2bf(tile[c][n]);
  }
}

// ---------------- bf16 MFMA GEMM (128x128 tile, BK=32) ----------------
template <int MODE>
__global__ __launch_bounds__(256) void gemm_bf16_kernel(const ushort* __restrict__ A,
                                                        const ushort* __restrict__ Bt,
                                                        float* __restrict__ C0,
                                                        ushort* __restrict__ C1,
                                                        ushort* __restrict__ C2,
                                                        ushort* __restrict__ C3) {
  __shared__ __align__(16) ushort As[128 * 32];
  __shared__ __align__(16) ushort Bs[128 * 32];
  const int tid = threadIdx.x;
  const int w = tid >> 6, l = tid & 63;
  const int lr = l & 15, lg = l >> 4;
  const int wr = w >> 1, wc = w & 1;
  const int n0 = blockIdx.x * 128;
  const int m0 = blockIdx.y * 128;
  constexpr int K = 1024;

  f32x4 acc[4][4];
#pragma unroll
  for (int i = 0; i < 4; ++i)
#pragma unroll
    for (int j = 0; j < 4; ++j) acc[i][j] = (f32x4){0.f, 0.f, 0.f, 0.f};

  const int e0 = w * 512 + l * 8;
  const int r0 = e0 >> 5, c0 = e0 & 31;
  const int e1 = 2048 + e0;
  const int r1 = e1 >> 5, c1 = e1 & 31;
  const ushort* a0p = A + (size_t)(m0 + r0) * K + c0;
  const ushort* a1p = A + (size_t)(m0 + r1) * K + c1;
  const ushort* b0p = Bt + (size_t)(n0 + r0) * K + c0;
  const ushort* b1p = Bt + (size_t)(n0 + r1) * K + c1;
  ushort* lA0 = &As[w * 512];
  ushort* lA1 = &As[2048 + w * 512];
  ushort* lB0 = &Bs[w * 512];
  ushort* lB1 = &Bs[2048 + w * 512];

  for (int k0 = 0; k0 < K; k0 += 32) {
    __syncthreads();
    gload16(a0p + k0, lA0);
    gload16(a1p + k0, lA1);
    gload16(b0p + k0, lB0);
    gload16(b1p + k0, lB1);
    __syncthreads();
    short8 af[4], bfr[4];
#pragma unroll
    for (int i = 0; i < 4; ++i) af[i] = *(const short8*)&As[(wr * 64 + i * 16 + lr) * 32 + lg * 8];
#pragma unroll
    for (int j = 0; j < 4; ++j) bfr[j] = *(const short8*)&Bs[(wc * 64 + j * 16 + lr) * 32 + lg * 8];
#pragma unroll
    for (int i = 0; i < 4; ++i)
#pragma unroll
      for (int j = 0; j < 4; ++j)
        acc[i][j] = __builtin_amdgcn_mfma_f32_16x16x32_bf16(af[i], bfr[j], acc[i][j], 0, 0, 0);
  }

  const int seg = n0 >> 10;
  const int nbase = n0 & 1023;
#pragma unroll
  for (int i = 0; i < 4; ++i)
#pragma unroll
    for (int j = 0; j < 4; ++j)
#pragma unroll
      for (int r2 = 0; r2 < 4; ++r2) {
        const int row = m0 + wr * 64 + i * 16 + lg * 4 + r2;
        const int col = wc * 64 + j * 16 + lr;
        float v = acc[i][j][r2];
        if (MODE == 0) {
          C0[(size_t)row * 1024 + n0 + col] = v;
        } else {
          const int nloc = nbase + col;
          if (seg == 0)      C1[(size_t)row * 1024 + nloc] = f2bf(v);
          else if (seg == 1) C0[(size_t)row * 1024 + nloc] = v;
          else if (seg == 2) C2[(size_t)row * 1024 + nloc] = f2bf(v);
          else {
            float s = v / (1.f + __expf(-v));
            C3[(size_t)row * 1024 + nloc] = f2bf(s);
          }
        }
      }
}

// ---------------- headwise LN over 128, fp32 k: in-place + bf16 copy + ||k||^2 ----------------
__global__ __launch_bounds__(256) void hln_kernel(float* __restrict__ buf,
                                                  ushort* __restrict__ kbf,
                                                  float* __restrict__ knorm2) {
  int lane = threadIdx.x & 63;
  size_t row = (size_t)blockIdx.x * 4 + (threadIdx.x >> 6);
  float* p = buf + row * 128;
  float2 v = *(float2*)(p + lane * 2);
  float s = v.x + v.y;
#pragma unroll
  for (int off = 32; off; off >>= 1) s += __shfl_down(s, off);
  float mu = __shfl(s, 0) * (1.f / 128.f);
  float dx = v.x - mu, dy = v.y - mu;
  float q = dx * dx + dy * dy;
#pragma unroll
  for (int off = 32; off; off >>= 1) q += __shfl_down(q, off);
  float qf = __shfl(q, 0);
  float rs = rsqrtf(qf * (1.f / 128.f) + 1e-6f);
  float ox = dx * rs, oy = dy * rs;
  *(float2*)(p + lane * 2) = make_float2(ox, oy);
  *(uint*)(kbf + row * 128 + lane * 2) = pk2(ox, oy);
  if (lane == 0) knorm2[row] = qf * rs * rs;
}

// ---------------- headwise LN over 128, bf16 in-place + xu (q path) ----------------
__global__ __launch_bounds__(256) void hln_bf_kernel(ushort* __restrict__ buf,
                                                     const float* __restrict__ xu) {
  int lane = threadIdx.x & 63;
  size_t row = (size_t)blockIdx.x * 4 + (threadIdx.x >> 6);
  ushort* p = buf + row * 128;
  uint u = *(uint*)(p + lane * 2);
  float vx = bf2f((ushort)(u & 0xffff)), vy = bf2f((ushort)(u >> 16));
  float s = vx + vy;
#pragma unroll
  for (int off = 32; off; off >>= 1) s += __shfl_down(s, off);
  float mu = __shfl(s, 0) * (1.f / 128.f);
  float dx = vx - mu, dy = vy - mu;
  float q = dx * dx + dy * dy;
#pragma unroll
  for (int off = 32; off; off >>= 1) q += __shfl_down(q, off);
  float rs = rsqrtf(__shfl(q, 0) * (1.f / 128.f) + 1e-6f);
  int h = (int)(row & 7);
  float ox = dx * rs + xu[h * 128 + lane * 2];
  float oy = dy * rs + xu[h * 128 + lane * 2 + 1];
  *(uint*)(p + lane * 2) = pk2(ox, oy);
}

// ---------------- codebook norms + bf16 copy ----------------
__global__ __launch_bounds__(128) void cbprep_kernel(const float* __restrict__ cb,
                                                     float* __restrict__ cbn,
                                                     ushort* __restrict__ cb_bf) {
  __shared__ float sm[2];
  const int hc = blockIdx.x;
  float v = cb[(size_t)hc * 128 + threadIdx.x];
  cb_bf[(size_t)hc * 128 + threadIdx.x] = f2bf(v);
  float s = v * v;
#pragma unroll
  for (int off = 32; off; off >>= 1) s += __shfl_down(s, off);
  if ((threadIdx.x & 63) == 0) sm[threadIdx.x >> 6] = s;
  __syncthreads();
  if (threadIdx.x == 0) cbn[hc] = sm[0] + sm[1];
}

// ---------------- MFMA VQ: argmin over 512 codes via k.c MFMA ----------------
// block = 4 waves, 64 t-rows of one (b,h); wave w owns rows w*16..w*16+16
__global__ __launch_bounds__(256) void vq_mfma_kernel(const ushort* __restrict__ kbf,
                                                      const ushort* __restrict__ cb_bf,
                                                      const float* __restrict__ cbn,
                                                      const float* __restrict__ knorm2,
                                                      const float* __restrict__ mask,
                                                      ushort* __restrict__ khat_bf,
                                                      float* __restrict__ blocksq) {
  __shared__ ushort Kb[64][136];
  __shared__ ushort Cb[64][136];
  __shared__ float cnsh[64];
  __shared__ int zsh[64];
  __shared__ float dsh[64];
  const int tid = threadIdx.x;
  const int w = tid >> 6, l = tid & 63;
  const int lr = l & 15, lg = l >> 4;
  const int b = blockIdx.y >> 3, h = blockIdx.y & 7;
  const int t0 = blockIdx.x * 64;
  const int srow = tid >> 2, sd = (tid & 3) * 32;

  {
    const ushort* src = kbf + ((size_t)((b * nT + t0 + srow) * nH + h)) * 128 + sd;
    *(uint4*)&Kb[srow][sd] = *(const uint4*)src;
    *(uint4*)&Kb[srow][sd + 8] = *(const uint4*)(src + 8);
    *(uint4*)&Kb[srow][sd + 16] = *(const uint4*)(src + 16);
    *(uint4*)&Kb[srow][sd + 24] = *(const uint4*)(src + 24);
  }
  __syncthreads();

  short8 af[4];
#pragma unroll
  for (int k0 = 0; k0 < 4; ++k0) af[k0] = *(const short8*)&Kb[w * 16 + lr][k0 * 32 + lg * 8];

  float best[4] = {1e30f, 1e30f, 1e30f, 1e30f};
  int bidx[4] = {0, 0, 0, 0};

  for (int cc = 0; cc < 8; ++cc) {
    __syncthreads();
    {
      const ushort* src = cb_bf + ((size_t)(h * nC + cc * 64 + srow)) * 128 + sd;
      *(uint4*)&Cb[srow][sd] = *(const uint4*)src;
      *(uint4*)&Cb[srow][sd + 8] = *(const uint4*)(src + 8);
      *(uint4*)&Cb[srow][sd + 16] = *(const uint4*)(src + 16);
      *(uint4*)&Cb[srow][sd + 24] = *(const uint4*)(src + 24);
      if (tid < 64) cnsh[tid] = cbn[h * nC + cc * 64 + tid];
    }
    __syncthreads();
#pragma unroll
    for (int ct = 0; ct < 4; ++ct) {
      f32x4 z = (f32x4){0.f, 0.f, 0.f, 0.f};
#pragma unroll
      for (int k0 = 0; k0 < 4; ++k0) {
        short8 cf = *(const short8*)&Cb[ct * 16 + lr][k0 * 32 + lg * 8];
        z = __builtin_amdgcn_mfma_f32_16x16x32_bf16(af[k0], cf, z, 0, 0, 0);
      }
      const int code = cc * 64 + ct * 16 + lr;
      const float cn = cnsh[ct * 16 + lr];
#pragma unroll
      for (int r2 = 0; r2 < 4; ++r2) {
        float d = cn - 2.f * z[r2];
        if (d < best[r2]) { best[r2] = d; bidx[r2] = code; }
      }
    }
  }

  // reduce across the 16 code-lanes sharing one row group (lowest index on ties)
#pragma unroll
  for (int off = 1; off < 16; off <<= 1) {
#pragma unroll
    for (int r2 = 0; r2 < 4; ++r2) {
      float od = __shfl_xor(best[r2], off);
      int oi = __shfl_xor(bidx[r2], off);
      if (od < best[r2] || (od == best[r2] && oi < bidx[r2])) { best[r2] = od; bidx[r2] = oi; }
    }
  }
  if (lr == 0) {
#pragma unroll
    for (int r2 = 0; r2 < 4; ++r2) {
      int row = w * 16 + lg * 4 + r2;
      zsh[row] = bidx[r2];
      dsh[row] = best[r2];
    }
  }
  __syncthreads();

  // gather khat (bf16)
  {
    const int row = tid >> 2, part = (tid & 3) * 32;
    const ushort* src = cb_bf + ((size_t)(h * nC + zsh[row])) * 128 + part;
    ushort* dst = khat_bf + ((size_t)((b * nT + t0 + row) * nH + h)) * 128 + part;
    *(uint4*)dst = *(const uint4*)src;
    *(uint4*)(dst + 8) = *(const uint4*)(src + 8);
    *(uint4*)(dst + 16) = *(const uint4*)(src + 16);
    *(uint4*)(dst + 24) = *(const uint4*)(src + 24);
  }

  // loss partial for this block
  if (tid < 64) {
    float s = mask[b * nT + t0 + tid] *
              (knorm2[(size_t)(b * nT + t0 + tid) * nH + h] + dsh[tid]);
#pragma unroll
    for (int off = 32; off; off >>= 1) s += __shfl_down(s, off);
    if (tid == 0) blocksq[blockIdx.y * gridDim.x + blockIdx.x] = s;
  }
}

// ---------------- MFMA flash attention (all K/V/Q operands bf16) ----------------
__global__ __launch_bounds__(256) void attn_mfma_kernel(
    const ushort* __restrict__ qb, const ushort* __restrict__ khat,
    const ushort* __restrict__ vbuf, const ushort* __restrict__ xlk,
    const ushort* __restrict__ xlv, const ushort* __restrict__ cbb,
    const ushort* __restrict__ aggU, const float* __restrict__ aggL,
    const ushort* __restrict__ gbuf, ushort* __restrict__ o) {
  __shared__ ushort Ks[64][136];
  __shared__ ushort Vts[128][72];
  __shared__ ushort Ps[4][16][72];
  __shared__ float lowb[64];

  const int tid = threadIdx.x;
  const int w = tid >> 6, l = tid & 63;
  const int lr = l & 15, lg = l >> 4;
  const int b = blockIdx.y >> 3, h = blockIdx.y & 7;
  const int t0 = blockIdx.x * 64;

  short8 qf[4];
  {
    const ushort* qrow = qb + ((size_t)((b * nT + t0 + w * 16 + lr) * nH + h)) * 128;
#pragma unroll
    for (int k0 = 0; k0 < 4; ++k0) qf[k0] = *(const short8*)(qrow + k0 * 32 + lg * 8);
  }

  float m_r[4] = {-1e30f, -1e30f, -1e30f, -1e30f};
  float l_r[4] = {0.f, 0.f, 0.f, 0.f};
  f32x4 acc_o[8];
#pragma unroll
  for (int dt = 0; dt < 8; ++dt) acc_o[dt] = (f32x4){0.f, 0.f, 0.f, 0.f};

  const int srow = tid >> 2, sd = (tid & 3) * 32;
  const int kp = tid & 31, dbase = (tid >> 5) * 16;

  auto stageK = [&](const ushort* src) {
#pragma unroll
    for (int q4 = 0; q4 < 4; ++q4)
      *(uint4*)&Ks[srow][sd + q4 * 8] = *(const uint4*)(src + q4 * 8);
  };
  auto stageVbf = [&](const ushort* v0, const ushort* v1) {
    short8 a0 = *(const short8*)(v0);
    short8 a1 = *(const short8*)(v0 + 8);
    short8 b0 = *(const short8*)(v1);
    short8 b1 = *(const short8*)(v1 + 8);
#pragma unroll
    for (int i2 = 0; i2 < 8; ++i2) {
      *(uint*)&Vts[dbase + i2][2 * kp] = (uint)(ushort)a0[i2] | ((uint)(ushort)b0[i2] << 16);
      *(uint*)&Vts[dbase + 8 + i2][2 * kp] = (uint)(ushort)a1[i2] | ((uint)(ushort)b1[i2] << 16);
    }
  };

  auto chunk_body = [&](int sbase, bool AGG, bool MASKQ) {
    f32x4 sc[4];
#pragma unroll
    for (int kt = 0; kt < 4; ++kt) {
      f32x4 z = (f32x4){0.f, 0.f, 0.f, 0.f};
#pragma unroll
      for (int k0 = 0; k0 < 4; ++k0) {
        short8 kf = *(const short8*)&Ks[kt * 16 + lr][k0 * 32 + lg * 8];
        z = __builtin_amdgcn_mfma_f32_16x16x32_bf16(qf[k0], kf, z, 0, 0, 0);
      }
      sc[kt] = z;
    }
    float sv[4][4];
    float pm[4] = {-1e30f, -1e30f, -1e30f, -1e30f};
#pragma unroll
    for (int kt = 0; kt < 4; ++kt)
#pragma unroll
      for (int r2 = 0; r2 < 4; ++r2) {
        float s = sc[kt][r2] * RTAU;
        if (MASKQ) {
          int key = sbase + kt * 16 + lr;
          int tl = t0 + w * 16 + lg * 4 + r2 + nM;
          if (key > tl) s = -1e30f;
        }
        sv[kt][r2] = s;
        pm[r2] = fmaxf(pm[r2], s);
      }
#pragma unroll
    for (int r2 = 0; r2 < 4; ++r2)
#pragma unroll
      for (int off = 1; off < 16; off <<= 1) pm[r2] = fmaxf(pm[r2], __shfl_xor(pm[r2], off));
    float scale[4], rs[4];
#pragma unroll
    for (int r2 = 0; r2 < 4; ++r2) {
      float mn = fmaxf(m_r[r2], pm[r2]);
      scale[r2] = __expf(m_r[r2] - mn);
      m_r[r2] = mn;
      rs[r2] = 0.f;
    }
#pragma unroll
    for (int kt = 0; kt < 4; ++kt)
#pragma unroll
      for (int r2 = 0; r2 < 4; ++r2) {
        float p = __expf(sv[kt][r2] - m_r[r2]);
        rs[r2] += AGG ? p * lowb[kt * 16 + lr] : p;
        Ps[w][lg * 4 + r2][kt * 16 + lr] = f2bf(p);
      }
#pragma unroll
    for (int r2 = 0; r2 < 4; ++r2)
#pragma unroll
      for (int off = 1; off < 16; off <<= 1) rs[r2] += __shfl_xor(rs[r2], off);
#pragma unroll
    for (int r2 = 0; r2 < 4; ++r2) l_r[r2] = l_r[r2] * scale[r2] + rs[r2];
#pragma unroll
    for (int dt = 0; dt < 8; ++dt)
#pragma unroll
      for (int r2 = 0; r2 < 4; ++r2) acc_o[dt][r2] *= scale[r2];
    short8 pa0 = *(const short8*)&Ps[w][lr][lg * 8];
    short8 pa1 = *(const short8*)&Ps[w][lr][32 + lg * 8];
#pragma unroll
    for (int dt = 0; dt < 8; ++dt) {
      short8 vf0 = *(const short8*)&Vts[dt * 16 + lr][lg * 8];
      short8 vf1 = *(const short8*)&Vts[dt * 16 + lr][32 + lg * 8];
      acc_o[dt] = __builtin_amdgcn_mfma_f32_16x16x32_bf16(pa0, vf0, acc_o[dt], 0, 0, 0);
      acc_o[dt] = __builtin_amdgcn_mfma_f32_16x16x32_bf16(pa1, vf1, acc_o[dt], 0, 0, 0);
    }
  };

  const int nch = t0 / 64 + 9;
  for (int ci = 0; ci < nch; ++ci) {
    const int sbase = ci * 64;
    __syncthreads();
    {
      int s = sbase + srow;
      const ushort* src = (s < nM)
          ? xlk + ((size_t)(b * nH + h) * nM + s) * 128 + sd
          : khat + ((size_t)((b * nT + (s - nM)) * nH + h)) * 128 + sd;
      stageK(src);
    }
    {
      int s0 = sbase + 2 * kp;
      if (s0 < nM) {
        const ushort* v0 = xlv + ((size_t)(b * nH + h) * nM + s0) * 128 + dbase;
        stageVbf(v0, v0 + 128);
      } else {
        const ushort* v0 = vbuf + ((size_t)((b * nT + (s0 - nM)) * nH + h)) * 128 + dbase;
        stageVbf(v0, v0 + nH * 128);
      }
    }
    __syncthreads();
    chunk_body(sbase, false, ci == nch - 1);
  }

  for (int ca = 0; ca < 8; ++ca) {
    const int sbase = ca * 64;
    __syncthreads();
    stageK(cbb + ((size_t)h * nC + sbase + srow) * 128 + sd);
    {
      const ushort* v0 = aggU + ((size_t)(b * nH + h) * nC + sbase + 2 * kp) * 128 + dbase;
      stageVbf(v0, v0 + 128);
    }
    if (tid < 64) lowb[tid] = aggL[(size_t)(b * nH + h) * nC + sbase + tid];
    __syncthreads();
    chunk_body(sbase, true, false);
  }

  float inv[4];
#pragma unroll
  for (int r2 = 0; r2 < 4; ++r2) inv[r2] = 1.f / l_r[r2];
#pragma unroll
  for (int dt = 0; dt < 8; ++dt)
#pragma unroll
    for (int r2 = 0; r2 < 4; ++r2) {
      int trow = t0 + w * 16 + lg * 4 + r2;
      size_t oi = ((size_t)(b * nT + trow)) * nD + h * 128 + dt * 16 + lr;
      float gv = bf2f(gbuf[oi]);
      o[oi] = f2bf(acc_o[dt][r2] * inv[r2] * gv);
    }
}

// ---------------- losses ----------------
__global__ __launch_bounds__(256) void finalize_kernel(const float* __restrict__ blocksq,
                                                       int nblk,
                                                       const float* __restrict__ mask,
                                                       float* __restrict__ outp) {
  __shared__ float sm[8];
  const int tid = threadIdx.x;
  float s = 0.f, ms = 0.f;
  for (int i = tid; i < NROW; i += 256) {
    if (i < nblk) s += blocksq[i];
    ms += mask[i];
  }
#pragma unroll
  for (int off = 32; off; off >>= 1) { s += __shfl_down(s, off); ms += __shfl_down(ms, off); }
  if ((tid & 63) == 0) { sm[tid >> 6] = s; sm[4 + (tid >> 6)] = ms; }
  __syncthreads();
  if (tid == 0) {
    float ts = sm[0] + sm[1] + sm[2] + sm[3];
    float tm = sm[4] + sm[5] + sm[6] + sm[7];
    float l = ts / (tm * (float)nH + 1e-6f);
    outp[0] = l;
    outp[1] = l;
  }
}

}  // namespace

extern "C" void kernel_launch(void* const* d_in, const int* in_sizes, int n_in,
                              void* d_out, int out_size, void* d_ws, size_t ws_size,
                              hipStream_t stream) {
  const float* x    = (const float*)d_in[0];
  const float* mask = (const float*)d_in[2];
  const float* xlk  = (const float*)d_in[3];
  const float* xlv  = (const float*)d_in[4];
  const float* aggU = (const float*)d_in[5];
  const float* aggL = (const float*)d_in[6];
  const float* wlng = (const float*)d_in[7];
  const float* wlnb = (const float*)d_in[8];
  const float* wq   = (const float*)d_in[9];
  const float* wk   = (const float*)d_in[10];
  const float* wv   = (const float*)d_in[11];
  const float* wg   = (const float*)d_in[12];
  const float* wres = (const float*)d_in[13];
  const float* xu   = (const float*)d_in[14];
  const float* cb   = (const float*)d_in[15];
  float* out = (float*)d_out;

  float* ws = (float*)d_ws;
  const size_t SZ = (size_t)NROW * nD;   // 4,194,304
  float*  kbuf    = ws;                                    // SZ floats
  ushort* qbuf_bf = (ushort*)(ws + SZ);                    // SZ ushorts
  ushort* khat_bf = (ushort*)(ws + SZ + SZ / 2);           // SZ ushorts
  ushort* vbuf_bf = (ushort*)(ws + 2 * SZ);                // SZ ushorts
  ushort* gbuf_bf = (ushort*)(ws + 2 * SZ + SZ / 2);       // SZ ushorts
  ushort* xt_bf   = (ushort*)(ws + 3 * SZ);                // SZ ushorts (kbf, obuf overlay)
  ushort* wqkvg_t = (ushort*)(ws + 3 * SZ + SZ / 2);       // 4096*1024 = SZ ushorts
  ushort* wres_t  = (ushort*)(ws + 4 * SZ);                // 1024*1024 ushorts
  ushort* xlk_bf  = (ushort*)(ws + 4 * SZ + SZ / 8);       // SZ ushorts
  ushort* xlv_bf  = (ushort*)(ws + 4 * SZ + SZ / 8 + SZ / 2);
  ushort* aggU_bf = (ushort*)(ws + 4 * SZ + SZ / 8 + SZ);
  ushort* cb_bf   = (ushort*)(ws + 4 * SZ + SZ / 8 + 3 * SZ / 2);  // 524288 ushorts
  float*  cbn     = ws + 4 * SZ + SZ / 8 + 3 * SZ / 2 + SZ / 16;   // 4096 floats
  float*  knorm2  = cbn + 4096;                            // 32768 floats
  float*  bsq     = knorm2 + 32768;                        // 512 floats
  // overlays: xt_bf dead after fused GEMM -> reused as kbf (hln->vq), then obuf (attn->final GEMM)
  ushort* kbf     = xt_bf;
  ushort* obuf_bf = xt_bf;

  ln_kernel<<<NROW, 256, 0, stream>>>(x, wlng, wlnb, xt_bf);
  wtrans_kernel<<<dim3(16, 16, 5), 256, 0, stream>>>(wq, wk, wv, wg, wres, wqkvg_t, wres_t);
  cbprep_kernel<<<nH * nC, 128, 0, stream>>>(cb, cbn, cb_bf);
  tobf_kernel<<<4096, 256, 0, stream>>>(xlk, xlk_bf);
  tobf_kernel<<<4096, 256, 0, stream>>>(xlv, xlv_bf);
  tobf_kernel<<<4096, 256, 0, stream>>>(aggU, aggU_bf);

  // fused q|k|v|g projection in bf16 MFMA (k written fp32 for hln/VQ path)
  gemm_bf16_kernel<1><<<dim3(32, 32), 256, 0, stream>>>(xt_bf, wqkvg_t, kbuf,
                                                        qbuf_bf, vbuf_bf, gbuf_bf);

  hln_bf_kernel<<<(NROW * nH) / 4, 256, 0, stream>>>(qbuf_bf, xu);
  hln_kernel<<<(NROW * nH) / 4, 256, 0, stream>>>(kbuf, kbf, knorm2);

  vq_mfma_kernel<<<dim3(nT / 64, nB * nH), 256, 0, stream>>>(kbf, cb_bf, cbn, knorm2,
                                                             mask, khat_bf, bsq);

  attn_mfma_kernel<<<dim3(nT / 64, nB * nH), 256, 0, stream>>>(
      qbuf_bf, khat_bf, vbuf_bf, xlk_bf, xlv_bf, cb_bf, aggU_bf, aggL, gbuf_bf, obuf_bf);

  gemm_bf16_kernel<0><<<dim3(8, 32), 256, 0, stream>>>(obuf_bf, wres_t, out,
                                                       nullptr, nullptr, nullptr);
  finalize_kernel<<<1, 256, 0, stream>>>(bsq, nT / 64 * nB * nH, mask, out + SZ);
}

// Round 10
// 250.448 us; speedup vs baseline: 6.3078x; 1.0426x over previous
//
#include <hip/hip_runtime.h>
#include <math.h>

namespace {

constexpr int nB = 8, nT = 512, nD = 1024, nH = 8, nDK = 128, nDV = 128, nC = 512, nM = 512;
constexpr int NROW = nB * nT;                  // 4096
constexpr float RTAU = 0.08838834764831845f;   // 1/sqrt(128)

typedef __attribute__((ext_vector_type(8))) short short8;
typedef __attribute__((ext_vector_type(4))) float f32x4;

__device__ __forceinline__ ushort f2bf(float f) {
  union { float f; uint u; } x; x.f = f;
  uint r = x.u + 0x7fff + ((x.u >> 16) & 1);
  return (ushort)(r >> 16);
}
__device__ __forceinline__ uint pk2(float a, float b) {
  return (uint)f2bf(a) | ((uint)f2bf(b) << 16);
}
__device__ __forceinline__ float bf2f(ushort u) {
  return __uint_as_float(((uint)u) << 16);
}
__device__ __forceinline__ void gload16(const void* g, void* l) {
  __builtin_amdgcn_global_load_lds((const __attribute__((address_space(1))) void*)g,
                                   (__attribute__((address_space(3))) void*)l, 16, 0, 0);
}

__device__ __forceinline__ float blockReduce256(float v, float* sm) {
  int lane = threadIdx.x & 63, w = threadIdx.x >> 6;
#pragma unroll
  for (int off = 32; off; off >>= 1) v += __shfl_down(v, off);
  if (lane == 0) sm[w] = v;
  __syncthreads();
  float r = sm[0] + sm[1] + sm[2] + sm[3];
  __syncthreads();
  return r;
}

// ---------------- LayerNorm -> bf16 xt ----------------
__global__ __launch_bounds__(256) void ln_kernel(const float* __restrict__ x,
                                                 const float* __restrict__ gw,
                                                 const float* __restrict__ bw,
                                                 ushort* __restrict__ xt_bf) {
  __shared__ float sm[4];
  size_t row = blockIdx.x;
  float4 v = ((const float4*)(x + row * nD))[threadIdx.x];
  float mu = blockReduce256(v.x + v.y + v.z + v.w, sm) * (1.f / nD);
  float4 d = make_float4(v.x - mu, v.y - mu, v.z - mu, v.w - mu);
  float var = blockReduce256(d.x * d.x + d.y * d.y + d.z * d.z + d.w * d.w, sm) * (1.f / nD);
  float rs = rsqrtf(var + 1e-6f);
  float4 gg = ((const float4*)gw)[threadIdx.x];
  float4 bb = ((const float4*)bw)[threadIdx.x];
  float4 o = make_float4(d.x * rs * gg.x + bb.x, d.y * rs * gg.y + bb.y,
                         d.z * rs * gg.z + bb.z, d.w * rs * gg.w + bb.w);
  uint2 pb;
  pb.x = pk2(o.x, o.y);
  pb.y = pk2(o.z, o.w);
  ((uint2*)(xt_bf + row * nD))[threadIdx.x] = pb;
}

// ---------------- fp32 -> bf16 cast, 3 buffers in one dispatch ----------------
__global__ __launch_bounds__(256) void tobf3_kernel(const float* __restrict__ s0,
                                                    ushort* __restrict__ d0,
                                                    const float* __restrict__ s1,
                                                    ushort* __restrict__ d1,
                                                    const float* __restrict__ s2,
                                                    ushort* __restrict__ d2) {
  const float* src = blockIdx.y == 0 ? s0 : (blockIdx.y == 1 ? s1 : s2);
  ushort* dst = blockIdx.y == 0 ? d0 : (blockIdx.y == 1 ? d1 : d2);
  size_t i = (size_t)blockIdx.x * 256 + threadIdx.x;
  float4 v = ((const float4*)src)[i];
  uint2 p;
  p.x = pk2(v.x, v.y);
  p.y = pk2(v.z, v.w);
  ((uint2*)dst)[i] = p;
}

// ---------------- weight transpose + bf16: D[n][k] = bf16(W[k][n]) ----------------
__global__ __launch_bounds__(256) void wtrans_kernel(const float* __restrict__ wq,
                                                     const float* __restrict__ wk,
                                                     const float* __restrict__ wv,
                                                     const float* __restrict__ wg,
                                                     const float* __restrict__ wres,
                                                     ushort* __restrict__ wqkvg_t,
                                                     ushort* __restrict__ wres_t) {
  __shared__ float tile[64][65];
  const int kz = blockIdx.x * 64;
  const int nz = blockIdx.y * 64;
  const float* W;
  ushort* D;
  if (blockIdx.z == 0)      { W = wq;   D = wqkvg_t; }
  else if (blockIdx.z == 1) { W = wk;   D = wqkvg_t + (size_t)1024 * 1024; }
  else if (blockIdx.z == 2) { W = wv;   D = wqkvg_t + (size_t)2048 * 1024; }
  else if (blockIdx.z == 3) { W = wg;   D = wqkvg_t + (size_t)3072 * 1024; }
  else                      { W = wres; D = wres_t; }
  const int c = threadIdx.x & 63, r4 = threadIdx.x >> 6;
#pragma unroll
  for (int i = 0; i < 16; ++i) {
    int r = i * 4 + r4;
    tile[r][c] = W[(size_t)(kz + r) * 1024 + nz + c];
  }
  __syncthreads();
#pragma unroll
  for (int i = 0; i < 16; ++i) {
    int n = i * 4 + r4;
    D[(size_t)(nz + n) * 1024 + kz + c] = f2bf(tile[c][n]);
  }
}

// ---------------- bf16 MFMA GEMM (128x128 tile, BK=32) ----------------
template <int MODE>
__global__ __launch_bounds__(256) void gemm_bf16_kernel(const ushort* __restrict__ A,
                                                        const ushort* __restrict__ Bt,
                                                        float* __restrict__ C0,
                                                        ushort* __restrict__ C1,
                                                        ushort* __restrict__ C2,
                                                        ushort* __restrict__ C3) {
  __shared__ __align__(16) ushort As[128 * 32];
  __shared__ __align__(16) ushort Bs[128 * 32];
  const int tid = threadIdx.x;
  const int w = tid >> 6, l = tid & 63;
  const int lr = l & 15, lg = l >> 4;
  const int wr = w >> 1, wc = w & 1;
  const int n0 = blockIdx.x * 128;
  const int m0 = blockIdx.y * 128;
  constexpr int K = 1024;

  f32x4 acc[4][4];
#pragma unroll
  for (int i = 0; i < 4; ++i)
#pragma unroll
    for (int j = 0; j < 4; ++j) acc[i][j] = (f32x4){0.f, 0.f, 0.f, 0.f};

  const int e0 = w * 512 + l * 8;
  const int r0 = e0 >> 5, c0 = e0 & 31;
  const int e1 = 2048 + e0;
  const int r1 = e1 >> 5, c1 = e1 & 31;
  const ushort* a0p = A + (size_t)(m0 + r0) * K + c0;
  const ushort* a1p = A + (size_t)(m0 + r1) * K + c1;
  const ushort* b0p = Bt + (size_t)(n0 + r0) * K + c0;
  const ushort* b1p = Bt + (size_t)(n0 + r1) * K + c1;
  ushort* lA0 = &As[w * 512];
  ushort* lA1 = &As[2048 + w * 512];
  ushort* lB0 = &Bs[w * 512];
  ushort* lB1 = &Bs[2048 + w * 512];

  for (int k0 = 0; k0 < K; k0 += 32) {
    __syncthreads();
    gload16(a0p + k0, lA0);
    gload16(a1p + k0, lA1);
    gload16(b0p + k0, lB0);
    gload16(b1p + k0, lB1);
    __syncthreads();
    short8 af[4], bfr[4];
#pragma unroll
    for (int i = 0; i < 4; ++i) af[i] = *(const short8*)&As[(wr * 64 + i * 16 + lr) * 32 + lg * 8];
#pragma unroll
    for (int j = 0; j < 4; ++j) bfr[j] = *(const short8*)&Bs[(wc * 64 + j * 16 + lr) * 32 + lg * 8];
    __builtin_amdgcn_s_setprio(1);
#pragma unroll
    for (int i = 0; i < 4; ++i)
#pragma unroll
      for (int j = 0; j < 4; ++j)
        acc[i][j] = __builtin_amdgcn_mfma_f32_16x16x32_bf16(af[i], bfr[j], acc[i][j], 0, 0, 0);
    __builtin_amdgcn_s_setprio(0);
  }

  const int seg = n0 >> 10;
  const int nbase = n0 & 1023;
#pragma unroll
  for (int i = 0; i < 4; ++i)
#pragma unroll
    for (int j = 0; j < 4; ++j)
#pragma unroll
      for (int r2 = 0; r2 < 4; ++r2) {
        const int row = m0 + wr * 64 + i * 16 + lg * 4 + r2;
        const int col = wc * 64 + j * 16 + lr;
        float v = acc[i][j][r2];
        if (MODE == 0) {
          C0[(size_t)row * 1024 + n0 + col] = v;
        } else {
          const int nloc = nbase + col;
          if (seg == 0)      C1[(size_t)row * 1024 + nloc] = f2bf(v);
          else if (seg == 1) C0[(size_t)row * 1024 + nloc] = v;
          else if (seg == 2) C2[(size_t)row * 1024 + nloc] = f2bf(v);
          else {
            float s = v / (1.f + __expf(-v));
            C3[(size_t)row * 1024 + nloc] = f2bf(s);
          }
        }
      }
}

// ---------------- headwise LN over 128, fp32 k: in-place + bf16 copy + ||k||^2 ----------------
__global__ __launch_bounds__(256) void hln_kernel(float* __restrict__ buf,
                                                  ushort* __restrict__ kbf,
                                                  float* __restrict__ knorm2) {
  int lane = threadIdx.x & 63;
  size_t row = (size_t)blockIdx.x * 4 + (threadIdx.x >> 6);
  float* p = buf + row * 128;
  float2 v = *(float2*)(p + lane * 2);
  float s = v.x + v.y;
#pragma unroll
  for (int off = 32; off; off >>= 1) s += __shfl_down(s, off);
  float mu = __shfl(s, 0) * (1.f / 128.f);
  float dx = v.x - mu, dy = v.y - mu;
  float q = dx * dx + dy * dy;
#pragma unroll
  for (int off = 32; off; off >>= 1) q += __shfl_down(q, off);
  float qf = __shfl(q, 0);
  float rs = rsqrtf(qf * (1.f / 128.f) + 1e-6f);
  float ox = dx * rs, oy = dy * rs;
  *(float2*)(p + lane * 2) = make_float2(ox, oy);
  *(uint*)(kbf + row * 128 + lane * 2) = pk2(ox, oy);
  if (lane == 0) knorm2[row] = qf * rs * rs;
}

// ---------------- headwise LN over 128, bf16 in-place + xu (q path) ----------------
__global__ __launch_bounds__(256) void hln_bf_kernel(ushort* __restrict__ buf,
                                                     const float* __restrict__ xu) {
  int lane = threadIdx.x & 63;
  size_t row = (size_t)blockIdx.x * 4 + (threadIdx.x >> 6);
  ushort* p = buf + row * 128;
  uint u = *(uint*)(p + lane * 2);
  float vx = bf2f((ushort)(u & 0xffff)), vy = bf2f((ushort)(u >> 16));
  float s = vx + vy;
#pragma unroll
  for (int off = 32; off; off >>= 1) s += __shfl_down(s, off);
  float mu = __shfl(s, 0) * (1.f / 128.f);
  float dx = vx - mu, dy = vy - mu;
  float q = dx * dx + dy * dy;
#pragma unroll
  for (int off = 32; off; off >>= 1) q += __shfl_down(q, off);
  float rs = rsqrtf(__shfl(q, 0) * (1.f / 128.f) + 1e-6f);
  int h = (int)(row & 7);
  float ox = dx * rs + xu[h * 128 + lane * 2];
  float oy = dy * rs + xu[h * 128 + lane * 2 + 1];
  *(uint*)(p + lane * 2) = pk2(ox, oy);
}

// ---------------- codebook norms + bf16 copy ----------------
__global__ __launch_bounds__(128) void cbprep_kernel(const float* __restrict__ cb,
                                                     float* __restrict__ cbn,
                                                     ushort* __restrict__ cb_bf) {
  __shared__ float sm[2];
  const int hc = blockIdx.x;
  float v = cb[(size_t)hc * 128 + threadIdx.x];
  cb_bf[(size_t)hc * 128 + threadIdx.x] = f2bf(v);
  float s = v * v;
#pragma unroll
  for (int off = 32; off; off >>= 1) s += __shfl_down(s, off);
  if ((threadIdx.x & 63) == 0) sm[threadIdx.x >> 6] = s;
  __syncthreads();
  if (threadIdx.x == 0) cbn[hc] = sm[0] + sm[1];
}

// ---------------- MFMA VQ: argmin over 512 codes via k.c MFMA ----------------
__global__ __launch_bounds__(256) void vq_mfma_kernel(const ushort* __restrict__ kbf,
                                                      const ushort* __restrict__ cb_bf,
                                                      const float* __restrict__ cbn,
                                                      const float* __restrict__ knorm2,
                                                      const float* __restrict__ mask,
                                                      ushort* __restrict__ khat_bf,
                                                      float* __restrict__ blocksq) {
  __shared__ ushort Kb[64][136];
  __shared__ ushort Cb[64][136];
  __shared__ float cnsh[64];
  __shared__ int zsh[64];
  __shared__ float dsh[64];
  const int tid = threadIdx.x;
  const int w = tid >> 6, l = tid & 63;
  const int lr = l & 15, lg = l >> 4;
  const int b = blockIdx.y >> 3, h = blockIdx.y & 7;
  const int t0 = blockIdx.x * 64;
  const int srow = tid >> 2, sd = (tid & 3) * 32;

  {
    const ushort* src = kbf + ((size_t)((b * nT + t0 + srow) * nH + h)) * 128 + sd;
    *(uint4*)&Kb[srow][sd] = *(const uint4*)src;
    *(uint4*)&Kb[srow][sd + 8] = *(const uint4*)(src + 8);
    *(uint4*)&Kb[srow][sd + 16] = *(const uint4*)(src + 16);
    *(uint4*)&Kb[srow][sd + 24] = *(const uint4*)(src + 24);
  }
  __syncthreads();

  short8 af[4];
#pragma unroll
  for (int k0 = 0; k0 < 4; ++k0) af[k0] = *(const short8*)&Kb[w * 16 + lr][k0 * 32 + lg * 8];

  float best[4] = {1e30f, 1e30f, 1e30f, 1e30f};
  int bidx[4] = {0, 0, 0, 0};

  for (int cc = 0; cc < 8; ++cc) {
    __syncthreads();
    {
      const ushort* src = cb_bf + ((size_t)(h * nC + cc * 64 + srow)) * 128 + sd;
      *(uint4*)&Cb[srow][sd] = *(const uint4*)src;
      *(uint4*)&Cb[srow][sd + 8] = *(const uint4*)(src + 8);
      *(uint4*)&Cb[srow][sd + 16] = *(const uint4*)(src + 16);
      *(uint4*)&Cb[srow][sd + 24] = *(const uint4*)(src + 24);
      if (tid < 64) cnsh[tid] = cbn[h * nC + cc * 64 + tid];
    }
    __syncthreads();
#pragma unroll
    for (int ct = 0; ct < 4; ++ct) {
      f32x4 z = (f32x4){0.f, 0.f, 0.f, 0.f};
#pragma unroll
      for (int k0 = 0; k0 < 4; ++k0) {
        short8 cf = *(const short8*)&Cb[ct * 16 + lr][k0 * 32 + lg * 8];
        z = __builtin_amdgcn_mfma_f32_16x16x32_bf16(af[k0], cf, z, 0, 0, 0);
      }
      const int code = cc * 64 + ct * 16 + lr;
      const float cn = cnsh[ct * 16 + lr];
#pragma unroll
      for (int r2 = 0; r2 < 4; ++r2) {
        float d = cn - 2.f * z[r2];
        if (d < best[r2]) { best[r2] = d; bidx[r2] = code; }
      }
    }
  }

#pragma unroll
  for (int off = 1; off < 16; off <<= 1) {
#pragma unroll
    for (int r2 = 0; r2 < 4; ++r2) {
      float od = __shfl_xor(best[r2], off);
      int oi = __shfl_xor(bidx[r2], off);
      if (od < best[r2] || (od == best[r2] && oi < bidx[r2])) { best[r2] = od; bidx[r2] = oi; }
    }
  }
  if (lr == 0) {
#pragma unroll
    for (int r2 = 0; r2 < 4; ++r2) {
      int row = w * 16 + lg * 4 + r2;
      zsh[row] = bidx[r2];
      dsh[row] = best[r2];
    }
  }
  __syncthreads();

  {
    const int row = tid >> 2, part = (tid & 3) * 32;
    const ushort* src = cb_bf + ((size_t)(h * nC + zsh[row])) * 128 + part;
    ushort* dst = khat_bf + ((size_t)((b * nT + t0 + row) * nH + h)) * 128 + part;
    *(uint4*)dst = *(const uint4*)src;
    *(uint4*)(dst + 8) = *(const uint4*)(src + 8);
    *(uint4*)(dst + 16) = *(const uint4*)(src + 16);
    *(uint4*)(dst + 24) = *(const uint4*)(src + 24);
  }

  if (tid < 64) {
    float s = mask[b * nT + t0 + tid] *
              (knorm2[(size_t)(b * nT + t0 + tid) * nH + h] + dsh[tid]);
#pragma unroll
    for (int off = 32; off; off >>= 1) s += __shfl_down(s, off);
    if (tid == 0) blocksq[blockIdx.y * gridDim.x + blockIdx.x] = s;
  }
}

// ---------------- MFMA flash attention ----------------
// grid = (bh, t0/64): linear block id = t0x*64 + bh -> id%8 = h, so all t0-blocks
// of one (b,h) land on one XCD (round-robin dispatch) and share K/V in its L2.
__global__ __launch_bounds__(256) void attn_mfma_kernel(
    const ushort* __restrict__ qb, const ushort* __restrict__ khat,
    const ushort* __restrict__ vbuf, const ushort* __restrict__ xlk,
    const ushort* __restrict__ xlv, const ushort* __restrict__ cbb,
    const ushort* __restrict__ aggU, const float* __restrict__ aggL,
    const ushort* __restrict__ gbuf, ushort* __restrict__ o) {
  __shared__ ushort Ks[64][136];
  __shared__ ushort Vts[128][72];
  __shared__ ushort Ps[4][16][72];
  __shared__ float lowb[64];

  const int tid = threadIdx.x;
  const int w = tid >> 6, l = tid & 63;
  const int lr = l & 15, lg = l >> 4;
  const int b = blockIdx.x >> 3, h = blockIdx.x & 7;
  const int t0 = blockIdx.y * 64;

  short8 qf[4];
  {
    const ushort* qrow = qb + ((size_t)((b * nT + t0 + w * 16 + lr) * nH + h)) * 128;
#pragma unroll
    for (int k0 = 0; k0 < 4; ++k0) qf[k0] = *(const short8*)(qrow + k0 * 32 + lg * 8);
  }

  float m_r[4] = {-1e30f, -1e30f, -1e30f, -1e30f};
  float l_r[4] = {0.f, 0.f, 0.f, 0.f};
  f32x4 acc_o[8];
#pragma unroll
  for (int dt = 0; dt < 8; ++dt) acc_o[dt] = (f32x4){0.f, 0.f, 0.f, 0.f};

  const int srow = tid >> 2, sd = (tid & 3) * 32;
  const int kp = tid & 31, dbase = (tid >> 5) * 16;

  auto stageK = [&](const ushort* src) {
#pragma unroll
    for (int q4 = 0; q4 < 4; ++q4)
      *(uint4*)&Ks[srow][sd + q4 * 8] = *(const uint4*)(src + q4 * 8);
  };
  auto stageVbf = [&](const ushort* v0, const ushort* v1) {
    short8 a0 = *(const short8*)(v0);
    short8 a1 = *(const short8*)(v0 + 8);
    short8 b0 = *(const short8*)(v1);
    short8 b1 = *(const short8*)(v1 + 8);
#pragma unroll
    for (int i2 = 0; i2 < 8; ++i2) {
      *(uint*)&Vts[dbase + i2][2 * kp] = (uint)(ushort)a0[i2] | ((uint)(ushort)b0[i2] << 16);
      *(uint*)&Vts[dbase + 8 + i2][2 * kp] = (uint)(ushort)a1[i2] | ((uint)(ushort)b1[i2] << 16);
    }
  };

  auto chunk_body = [&](int sbase, bool AGG, bool MASKQ) {
    f32x4 sc[4];
    __builtin_amdgcn_s_setprio(1);
#pragma unroll
    for (int kt = 0; kt < 4; ++kt) {
      f32x4 z = (f32x4){0.f, 0.f, 0.f, 0.f};
#pragma unroll
      for (int k0 = 0; k0 < 4; ++k0) {
        short8 kf = *(const short8*)&Ks[kt * 16 + lr][k0 * 32 + lg * 8];
        z = __builtin_amdgcn_mfma_f32_16x16x32_bf16(qf[k0], kf, z, 0, 0, 0);
      }
      sc[kt] = z;
    }
    __builtin_amdgcn_s_setprio(0);
    float sv[4][4];
    float pm[4] = {-1e30f, -1e30f, -1e30f, -1e30f};
#pragma unroll
    for (int kt = 0; kt < 4; ++kt)
#pragma unroll
      for (int r2 = 0; r2 < 4; ++r2) {
        float s = sc[kt][r2] * RTAU;
        if (MASKQ) {
          int key = sbase + kt * 16 + lr;
          int tl = t0 + w * 16 + lg * 4 + r2 + nM;
          if (key > tl) s = -1e30f;
        }
        sv[kt][r2] = s;
        pm[r2] = fmaxf(pm[r2], s);
      }
#pragma unroll
    for (int r2 = 0; r2 < 4; ++r2)
#pragma unroll
      for (int off = 1; off < 16; off <<= 1) pm[r2] = fmaxf(pm[r2], __shfl_xor(pm[r2], off));
    float scale[4], rs[4];
#pragma unroll
    for (int r2 = 0; r2 < 4; ++r2) {
      float mn = fmaxf(m_r[r2], pm[r2]);
      scale[r2] = __expf(m_r[r2] - mn);
      m_r[r2] = mn;
      rs[r2] = 0.f;
    }
#pragma unroll
    for (int kt = 0; kt < 4; ++kt)
#pragma unroll
      for (int r2 = 0; r2 < 4; ++r2) {
        float p = __expf(sv[kt][r2] - m_r[r2]);
        rs[r2] += AGG ? p * lowb[kt * 16 + lr] : p;
        Ps[w][lg * 4 + r2][kt * 16 + lr] = f2bf(p);
      }
#pragma unroll
    for (int r2 = 0; r2 < 4; ++r2)
#pragma unroll
      for (int off = 1; off < 16; off <<= 1) rs[r2] += __shfl_xor(rs[r2], off);
#pragma unroll
    for (int r2 = 0; r2 < 4; ++r2) l_r[r2] = l_r[r2] * scale[r2] + rs[r2];
#pragma unroll
    for (int dt = 0; dt < 8; ++dt)
#pragma unroll
      for (int r2 = 0; r2 < 4; ++r2) acc_o[dt][r2] *= scale[r2];
    short8 pa0 = *(const short8*)&Ps[w][lr][lg * 8];
    short8 pa1 = *(const short8*)&Ps[w][lr][32 + lg * 8];
    __builtin_amdgcn_s_setprio(1);
#pragma unroll
    for (int dt = 0; dt < 8; ++dt) {
      short8 vf0 = *(const short8*)&Vts[dt * 16 + lr][lg * 8];
      short8 vf1 = *(const short8*)&Vts[dt * 16 + lr][32 + lg * 8];
      acc_o[dt] = __builtin_amdgcn_mfma_f32_16x16x32_bf16(pa0, vf0, acc_o[dt], 0, 0, 0);
      acc_o[dt] = __builtin_amdgcn_mfma_f32_16x16x32_bf16(pa1, vf1, acc_o[dt], 0, 0, 0);
    }
    __builtin_amdgcn_s_setprio(0);
  };

  const int nch = t0 / 64 + 9;
  for (int ci = 0; ci < nch; ++ci) {
    const int sbase = ci * 64;
    __syncthreads();
    {
      int s = sbase + srow;
      const ushort* src = (s < nM)
          ? xlk + ((size_t)(b * nH + h) * nM + s) * 128 + sd
          : khat + ((size_t)((b * nT + (s - nM)) * nH + h)) * 128 + sd;
      stageK(src);
    }
    {
      int s0 = sbase + 2 * kp;
      if (s0 < nM) {
        const ushort* v0 = xlv + ((size_t)(b * nH + h) * nM + s0) * 128 + dbase;
        stageVbf(v0, v0 + 128);
      } else {
        const ushort* v0 = vbuf + ((size_t)((b * nT + (s0 - nM)) * nH + h)) * 128 + dbase;
        stageVbf(v0, v0 + nH * 128);
      }
    }
    __syncthreads();
    chunk_body(sbase, false, ci == nch - 1);
  }

  for (int ca = 0; ca < 8; ++ca) {
    const int sbase = ca * 64;
    __syncthreads();
    stageK(cbb + ((size_t)h * nC + sbase + srow) * 128 + sd);
    {
      const ushort* v0 = aggU + ((size_t)(b * nH + h) * nC + sbase + 2 * kp) * 128 + dbase;
      stageVbf(v0, v0 + 128);
    }
    if (tid < 64) lowb[tid] = aggL[(size_t)(b * nH + h) * nC + sbase + tid];
    __syncthreads();
    chunk_body(sbase, true, false);
  }

  float inv[4];
#pragma unroll
  for (int r2 = 0; r2 < 4; ++r2) inv[r2] = 1.f / l_r[r2];
#pragma unroll
  for (int dt = 0; dt < 8; ++dt)
#pragma unroll
    for (int r2 = 0; r2 < 4; ++r2) {
      int trow = t0 + w * 16 + lg * 4 + r2;
      size_t oi = ((size_t)(b * nT + trow)) * nD + h * 128 + dt * 16 + lr;
      float gv = bf2f(gbuf[oi]);
      o[oi] = f2bf(acc_o[dt][r2] * inv[r2] * gv);
    }
}

// ---------------- losses ----------------
__global__ __launch_bounds__(256) void finalize_kernel(const float* __restrict__ blocksq,
                                                       int nblk,
                                                       const float* __restrict__ mask,
                                                       float* __restrict__ outp) {
  __shared__ float sm[8];
  const int tid = threadIdx.x;
  float s = 0.f, ms = 0.f;
  for (int i = tid; i < NROW; i += 256) {
    if (i < nblk) s += blocksq[i];
    ms += mask[i];
  }
#pragma unroll
  for (int off = 32; off; off >>= 1) { s += __shfl_down(s, off); ms += __shfl_down(ms, off); }
  if ((tid & 63) == 0) { sm[tid >> 6] = s; sm[4 + (tid >> 6)] = ms; }
  __syncthreads();
  if (tid == 0) {
    float ts = sm[0] + sm[1] + sm[2] + sm[3];
    float tm = sm[4] + sm[5] + sm[6] + sm[7];
    float l = ts / (tm * (float)nH + 1e-6f);
    outp[0] = l;
    outp[1] = l;
  }
}

}  // namespace

extern "C" void kernel_launch(void* const* d_in, const int* in_sizes, int n_in,
                              void* d_out, int out_size, void* d_ws, size_t ws_size,
                              hipStream_t stream) {
  const float* x    = (const float*)d_in[0];
  const float* mask = (const float*)d_in[2];
  const float* xlk  = (const float*)d_in[3];
  const float* xlv  = (const float*)d_in[4];
  const float* aggU = (const float*)d_in[5];
  const float* aggL = (const float*)d_in[6];
  const float* wlng = (const float*)d_in[7];
  const float* wlnb = (const float*)d_in[8];
  const float* wq   = (const float*)d_in[9];
  const float* wk   = (const float*)d_in[10];
  const float* wv   = (const float*)d_in[11];
  const float* wg   = (const float*)d_in[12];
  const float* wres = (const float*)d_in[13];
  const float* xu   = (const float*)d_in[14];
  const float* cb   = (const float*)d_in[15];
  float* out = (float*)d_out;

  float* ws = (float*)d_ws;
  const size_t SZ = (size_t)NROW * nD;   // 4,194,304
  float*  kbuf    = ws;                                    // SZ floats
  ushort* qbuf_bf = (ushort*)(ws + SZ);                    // SZ ushorts
  ushort* khat_bf = (ushort*)(ws + SZ + SZ / 2);           // SZ ushorts
  ushort* vbuf_bf = (ushort*)(ws + 2 * SZ);                // SZ ushorts
  ushort* gbuf_bf = (ushort*)(ws + 2 * SZ + SZ / 2);       // SZ ushorts
  ushort* xt_bf   = (ushort*)(ws + 3 * SZ);                // SZ ushorts (kbf, obuf overlay)
  ushort* wqkvg_t = (ushort*)(ws + 3 * SZ + SZ / 2);       // 4096*1024 = SZ ushorts
  ushort* wres_t  = (ushort*)(ws + 4 * SZ);                // 1024*1024 ushorts
  ushort* xlk_bf  = (ushort*)(ws + 4 * SZ + SZ / 8);       // SZ ushorts
  ushort* xlv_bf  = (ushort*)(ws + 4 * SZ + SZ / 8 + SZ / 2);
  ushort* aggU_bf = (ushort*)(ws + 4 * SZ + SZ / 8 + SZ);
  ushort* cb_bf   = (ushort*)(ws + 4 * SZ + SZ / 8 + 3 * SZ / 2);  // 524288 ushorts
  float*  cbn     = ws + 4 * SZ + SZ / 8 + 3 * SZ / 2 + SZ / 16;   // 4096 floats
  float*  knorm2  = cbn + 4096;                            // 32768 floats
  float*  bsq     = knorm2 + 32768;                        // 512 floats
  ushort* kbf     = xt_bf;
  ushort* obuf_bf = xt_bf;

  ln_kernel<<<NROW, 256, 0, stream>>>(x, wlng, wlnb, xt_bf);
  wtrans_kernel<<<dim3(16, 16, 5), 256, 0, stream>>>(wq, wk, wv, wg, wres, wqkvg_t, wres_t);
  cbprep_kernel<<<nH * nC, 128, 0, stream>>>(cb, cbn, cb_bf);
  tobf3_kernel<<<dim3(4096, 3), 256, 0, stream>>>(xlk, xlk_bf, xlv, xlv_bf, aggU, aggU_bf);

  gemm_bf16_kernel<1><<<dim3(32, 32), 256, 0, stream>>>(xt_bf, wqkvg_t, kbuf,
                                                        qbuf_bf, vbuf_bf, gbuf_bf);

  hln_bf_kernel<<<(NROW * nH) / 4, 256, 0, stream>>>(qbuf_bf, xu);
  hln_kernel<<<(NROW * nH) / 4, 256, 0, stream>>>(kbuf, kbf, knorm2);

  vq_mfma_kernel<<<dim3(nT / 64, nB * nH), 256, 0, stream>>>(kbf, cb_bf, cbn, knorm2,
                                                             mask, khat_bf, bsq);

  attn_mfma_kernel<<<dim3(nB * nH, nT / 64), 256, 0, stream>>>(
      qbuf_bf, khat_bf, vbuf_bf, xlk_bf, xlv_bf, cb_bf, aggU_bf, aggL, gbuf_bf, obuf_bf);

  gemm_bf16_kernel<0><<<dim3(8, 32), 256, 0, stream>>>(obuf_bf, wres_t, out,
                                                       nullptr, nullptr, nullptr);
  finalize_kernel<<<1, 256, 0, stream>>>(bsq, nT / 64 * nB * nH, mask, out + SZ);
}